// Round 1
// 1830.347 us; speedup vs baseline: 1.0605x; 1.0605x over previous
//
#include <hip/hip_runtime.h>
#include <math.h>

#define N_PIX 65536
#define S_SP  1024
#define C_IN  128
#define HIDE  128
#define OUTW  64
#define NCLS  16
#define E_A   16384
#define E_IMP 6144
#define E_PX  1048576
#define EPSV  1e-5f

typedef __attribute__((ext_vector_type(4))) float f32x4;
typedef __attribute__((ext_vector_type(8))) short bf16x8;

__device__ inline ushort f2bf(float f) {
  uint u = __builtin_bit_cast(uint, f);
  uint r = (u + 0x7FFFu + ((u >> 16) & 1u)) >> 16;
  return (ushort)r;
}

// ---------------------------------------------------------------------------
// x0 = BN0(x @ prelin_w + prelin_b)       [N,128] @ [128,128]  (fp32)
// ---------------------------------------------------------------------------
__global__ __launch_bounds__(256) void k_x0(
    const float* __restrict__ x, const float* __restrict__ W,
    const float* __restrict__ bias, const float* __restrict__ g,
    const float* __restrict__ bb, const float* __restrict__ m,
    const float* __restrict__ vv, float* __restrict__ out) {
  __shared__ float Wl[128 * 128];
  __shared__ float Xl[32 * 128];
  int t = threadIdx.x;
  int n0 = blockIdx.x * 32;
  {
    const float4* Wg = (const float4*)W;
    float4* Wd = (float4*)Wl;
#pragma unroll
    for (int i = 0; i < 16; ++i) Wd[t + 256 * i] = Wg[t + 256 * i];
    const float4* Xg = (const float4*)(x + (size_t)n0 * 128);
    float4* Xd = (float4*)Xl;
#pragma unroll
    for (int i = 0; i < 4; ++i) Xd[t + 256 * i] = Xg[t + 256 * i];
  }
  __syncthreads();
  int ht = t & 31, nt = t >> 5;
  int h0 = ht * 4, r0 = nt * 4;
  float acc[4][4];
#pragma unroll
  for (int c = 0; c < 4; ++c) {
    float bv = bias[h0 + c];
#pragma unroll
    for (int r = 0; r < 4; ++r) acc[r][c] = bv;
  }
  for (int k = 0; k < 128; k += 4) {
    float4 xr[4], wk[4];
#pragma unroll
    for (int r = 0; r < 4; ++r) xr[r] = *(const float4*)&Xl[(r0 + r) * 128 + k];
#pragma unroll
    for (int kk = 0; kk < 4; ++kk) wk[kk] = *(const float4*)&Wl[(k + kk) * 128 + h0];
#pragma unroll
    for (int r = 0; r < 4; ++r) {
      float xs[4] = {xr[r].x, xr[r].y, xr[r].z, xr[r].w};
#pragma unroll
      for (int kk = 0; kk < 4; ++kk) {
        acc[r][0] += xs[kk] * wk[kk].x;
        acc[r][1] += xs[kk] * wk[kk].y;
        acc[r][2] += xs[kk] * wk[kk].z;
        acc[r][3] += xs[kk] * wk[kk].w;
      }
    }
  }
#pragma unroll
  for (int c = 0; c < 4; ++c) {
    int h = h0 + c;
    float sc = g[h] * rsqrtf(vv[h] + EPSV);
    float mb = m[h], bo = bb[h];
#pragma unroll
    for (int r = 0; r < 4; ++r) acc[r][c] = sc * (acc[r][c] - mb) + bo;
  }
#pragma unroll
  for (int r = 0; r < 4; ++r) {
    *(float4*)&out[(size_t)(n0 + r0 + r) * 128 + h0] =
        make_float4(acc[r][0], acc[r][1], acc[r][2], acc[r][3]);
  }
}

// ---------------------------------------------------------------------------
// k_cast: Q fp32 [N,1024] -> Qt bf16 [1024][N] + csum[s] (exact fp32 col sums)
// Optionally also emits Qbf bf16 [N][1024] (row-major) for k_hyp_bf.
// block tile: 256 n x 64 s; per-thread 4x4 register micro-transpose.
// ---------------------------------------------------------------------------
__global__ __launch_bounds__(256) void k_cast(
    const float* __restrict__ Q, ushort* __restrict__ Qt,
    float* __restrict__ csum, ushort* __restrict__ Qbf) {
  __shared__ ushort Ot[64 * 258];  // [s][n] pad 2
  __shared__ float Cs[64];
  int t = threadIdx.x;
  int nt = blockIdx.x & 255, st = blockIdx.x >> 8;
  int n0 = nt * 256, s0 = st * 64;
  int lr = t & 15, lg = t >> 4;
  if (t < 64) Cs[t] = 0.f;
  __syncthreads();
  float sums[4] = {0.f, 0.f, 0.f, 0.f};
#pragma unroll
  for (int nb = 0; nb < 4; ++nb) {
    ushort hh[4][4];
#pragma unroll
    for (int u = 0; u < 4; ++u) {
      int n = n0 + nb * 64 + lg * 4 + u;
      float4 q = *(const float4*)&Q[(size_t)n * 1024 + s0 + lr * 4];
      sums[0] += q.x; sums[1] += q.y; sums[2] += q.z; sums[3] += q.w;
      hh[u][0] = f2bf(q.x); hh[u][1] = f2bf(q.y);
      hh[u][2] = f2bf(q.z); hh[u][3] = f2bf(q.w);
      if (Qbf) {
        uint2 w;
        w.x = (uint)hh[u][0] | ((uint)hh[u][1] << 16);
        w.y = (uint)hh[u][2] | ((uint)hh[u][3] << 16);
        *(uint2*)&Qbf[(size_t)n * 1024 + s0 + lr * 4] = w;
      }
    }
#pragma unroll
    for (int v = 0; v < 4; ++v) {
      uint lo = (uint)hh[0][v] | ((uint)hh[1][v] << 16);
      uint hi = (uint)hh[2][v] | ((uint)hh[3][v] << 16);
      ushort* p = &Ot[(lr * 4 + v) * 258 + nb * 64 + lg * 4];
      *(uint*)p = lo;
      *(uint*)(p + 2) = hi;
    }
  }
#pragma unroll
  for (int v = 0; v < 4; ++v) atomicAdd(&Cs[lr * 4 + v], sums[v]);
  __syncthreads();
  if (t < 64) atomicAdd(&csum[s0 + t], Cs[t]);
#pragma unroll
  for (int i = 0; i < 16; ++i) {
    int v2 = i * 256 + t;
    int s_loc = v2 >> 6, nq = v2 & 63;
    const ushort* p = &Ot[s_loc * 258 + nq * 4];
    uint2 o;
    o.x = *(const uint*)p;
    o.y = *(const uint*)(p + 2);
    *(uint2*)&Qt[(size_t)(s0 + s_loc) * 65536 + n0 + nq * 4] = o;
  }
}

// ---------------------------------------------------------------------------
// k_xT: x0 fp32 [N,128] -> x0T bf16 [128][N]
// ---------------------------------------------------------------------------
__global__ __launch_bounds__(256) void k_xT(
    const float* __restrict__ x0, ushort* __restrict__ x0T) {
  __shared__ ushort Ot[128 * 258];  // 66 KB
  int t = threadIdx.x;
  int n0 = blockIdx.x * 256;
  int lr = t & 31, lg = t >> 5;
#pragma unroll
  for (int nb = 0; nb < 8; ++nb) {
    ushort hh[4][4];
#pragma unroll
    for (int u = 0; u < 4; ++u) {
      int n = n0 + nb * 32 + lg * 4 + u;
      float4 q = *(const float4*)&x0[(size_t)n * 128 + lr * 4];
      hh[u][0] = f2bf(q.x); hh[u][1] = f2bf(q.y);
      hh[u][2] = f2bf(q.z); hh[u][3] = f2bf(q.w);
    }
#pragma unroll
    for (int v = 0; v < 4; ++v) {
      uint lo = (uint)hh[0][v] | ((uint)hh[1][v] << 16);
      uint hi = (uint)hh[2][v] | ((uint)hh[3][v] << 16);
      ushort* p = &Ot[(lr * 4 + v) * 258 + nb * 32 + lg * 4];
      *(uint*)p = lo;
      *(uint*)(p + 2) = hi;
    }
  }
  __syncthreads();
#pragma unroll
  for (int i = 0; i < 32; ++i) {
    int v2 = i * 256 + t;
    int h = v2 >> 6, nq = v2 & 63;
    const ushort* p = &Ot[h * 258 + nq * 4];
    uint2 o;
    o.x = *(const uint*)p;
    o.y = *(const uint*)(p + 2);
    *(uint2*)&x0T[(size_t)h * 65536 + n0 + nq * 4] = o;
  }
}

// ---------------------------------------------------------------------------
// k_hpT: hp fp32 [1024][128] -> hpT bf16 [128][1024]
// ---------------------------------------------------------------------------
__global__ __launch_bounds__(256) void k_hpT(
    const float* __restrict__ hp, ushort* __restrict__ hpT) {
  __shared__ ushort Ot[128 * 258];
  int t = threadIdx.x;
  int s0 = blockIdx.x * 256;
  int lr = t & 31, lg = t >> 5;
#pragma unroll
  for (int sb = 0; sb < 8; ++sb) {
    ushort hh[4][4];
#pragma unroll
    for (int u = 0; u < 4; ++u) {
      int s = s0 + sb * 32 + lg * 4 + u;
      float4 q = *(const float4*)&hp[(size_t)s * 128 + lr * 4];
      hh[u][0] = f2bf(q.x); hh[u][1] = f2bf(q.y);
      hh[u][2] = f2bf(q.z); hh[u][3] = f2bf(q.w);
    }
#pragma unroll
    for (int v = 0; v < 4; ++v) {
      uint lo = (uint)hh[0][v] | ((uint)hh[1][v] << 16);
      uint hi = (uint)hh[2][v] | ((uint)hh[3][v] << 16);
      ushort* p = &Ot[(lr * 4 + v) * 258 + sb * 32 + lg * 4];
      *(uint*)p = lo;
      *(uint*)(p + 2) = hi;
    }
  }
  __syncthreads();
#pragma unroll
  for (int i = 0; i < 32; ++i) {
    int v2 = i * 256 + t;
    int h = v2 >> 6, sq = v2 & 63;
    const ushort* p = &Ot[h * 258 + sq * 4];
    uint2 o;
    o.x = *(const uint*)p;
    o.y = *(const uint*)(p + 2);
    *(uint2*)&hpT[(size_t)h * 1024 + s0 + sq * 4] = o;
  }
}

// ---------------------------------------------------------------------------
// Shared MFMA core for the 128x128-out pipelined GEMM tiles.
// LDS tiles are [128 rows][72 shorts] (64 k-elems, +8 pad -> conflict-free).
// 4 waves as 2x2: wave (wr,wc) owns 64x64 of the 128x128 output.
// ---------------------------------------------------------------------------
__device__ __forceinline__ void mfma_tile128(const ushort* Al, const ushort* Bl,
                                             f32x4 acc[4][4], int wr, int wc,
                                             int lr, int lq) {
#pragma unroll
  for (int kh = 0; kh < 2; ++kh) {
    bf16x8 af[4], bf[4];
#pragma unroll
    for (int i = 0; i < 4; ++i)
      af[i] = *(const bf16x8*)&Al[(wr * 64 + i * 16 + lr) * 72 + kh * 32 + lq * 8];
#pragma unroll
    for (int j = 0; j < 4; ++j)
      bf[j] = *(const bf16x8*)&Bl[(wc * 64 + j * 16 + lr) * 72 + kh * 32 + lq * 8];
#pragma unroll
    for (int i = 0; i < 4; ++i)
#pragma unroll
      for (int j = 0; j < 4; ++j)
        acc[i][j] = __builtin_amdgcn_mfma_f32_16x16x32_bf16(af[i], bf[j],
                                                            acc[i][j], 0, 0, 0);
  }
}

// ---------------------------------------------------------------------------
// k_hpu2: hp_part[kb][s][h] = Qt[s-tile][n-chunk] . x0T[h][n-chunk]^T
// grid = 8 (s-tiles of 128) x 64 (k-splits of 1024 n) = 512 blocks (2/CU).
// 2-phase reg-staged double-buffered pipeline, 1 barrier per K-chunk.
// ---------------------------------------------------------------------------
__global__ __launch_bounds__(256) void k_hpu2(
    const ushort* __restrict__ Qt, const ushort* __restrict__ x0T,
    float* __restrict__ hp_part) {
  __shared__ ushort Al[2][128 * 72];
  __shared__ ushort Bl[2][128 * 72];
  int t = threadIdx.x;
  int st = blockIdx.x & 7, kb = blockIdx.x >> 3;
  int s0 = st * 128;
  int wv = t >> 6, lane = t & 63;
  int wr = wv >> 1, wc = wv & 1;
  int lr = lane & 15, lq = lane >> 4;
  int sr = t >> 3, sg = t & 7;  // staging: rows sr+32i, 16B granule sg
  const ushort* Ab = Qt + (size_t)(s0 + sr) * 65536 + (size_t)kb * 1024 + sg * 8;
  const ushort* Bb = x0T + (size_t)sr * 65536 + (size_t)kb * 1024 + sg * 8;
  f32x4 acc[4][4];
#pragma unroll
  for (int i = 0; i < 4; ++i)
#pragma unroll
    for (int j = 0; j < 4; ++j) acc[i][j] = (f32x4){0.f, 0.f, 0.f, 0.f};
  uint4 ra[4], rb[4];
#pragma unroll
  for (int i = 0; i < 4; ++i) {
    ra[i] = *(const uint4*)(Ab + (size_t)i * 32 * 65536);
    rb[i] = *(const uint4*)(Bb + (size_t)i * 32 * 65536);
  }
#pragma unroll
  for (int i = 0; i < 4; ++i) {
    *(uint4*)&Al[0][(sr + 32 * i) * 72 + sg * 8] = ra[i];
    *(uint4*)&Bl[0][(sr + 32 * i) * 72 + sg * 8] = rb[i];
  }
  __syncthreads();
  for (int c = 0; c < 16; ++c) {
    int p = c & 1;
    if (c < 15) {
      int ko = (c + 1) * 64;
#pragma unroll
      for (int i = 0; i < 4; ++i) {
        ra[i] = *(const uint4*)(Ab + (size_t)i * 32 * 65536 + ko);
        rb[i] = *(const uint4*)(Bb + (size_t)i * 32 * 65536 + ko);
      }
    }
    mfma_tile128(Al[p], Bl[p], acc, wr, wc, lr, lq);
    if (c < 15) {
      int q = p ^ 1;
#pragma unroll
      for (int i = 0; i < 4; ++i) {
        *(uint4*)&Al[q][(sr + 32 * i) * 72 + sg * 8] = ra[i];
        *(uint4*)&Bl[q][(sr + 32 * i) * 72 + sg * 8] = rb[i];
      }
    }
    __syncthreads();
  }
  float* outp = hp_part + (size_t)kb * 131072;
#pragma unroll
  for (int i = 0; i < 4; ++i) {
    int s_g = s0 + wr * 64 + i * 16 + lq * 4;
#pragma unroll
    for (int j = 0; j < 4; ++j) {
      int h = wc * 64 + j * 16 + lr;
#pragma unroll
      for (int r = 0; r < 4; ++r)
        outp[(size_t)(s_g + r) * 128 + h] = acc[i][j][r];
    }
  }
}

__global__ void k_hpred(const float* __restrict__ part,
                        const float* __restrict__ csum, float* __restrict__ hp) {
  int tid = blockIdx.x * 256 + threadIdx.x;
  float s = 0.f;
  for (int kb = 0; kb < 64; ++kb) s += part[(size_t)kb * 131072 + tid];
  hp[tid] = s / csum[tid >> 7];
}

// ---------------------------------------------------------------------------
// k_hyp_bf: hyp[n][h] = Qbf[n][s] . hpT[h][s]^T   (A pre-cast bf16)
// grid 512 (n-tiles of 128), 2-phase pipeline, 2 blocks/CU.
// ---------------------------------------------------------------------------
__global__ __launch_bounds__(256) void k_hyp_bf(
    const ushort* __restrict__ Qbf, const ushort* __restrict__ hpT,
    float* __restrict__ hyp) {
  __shared__ ushort Al[2][128 * 72];
  __shared__ ushort Bl[2][128 * 72];
  int t = threadIdx.x;
  int n0 = blockIdx.x * 128;
  int wv = t >> 6, lane = t & 63;
  int wr = wv >> 1, wc = wv & 1;
  int lr = lane & 15, lq = lane >> 4;
  int sr = t >> 3, sg = t & 7;
  const ushort* Ab = Qbf + (size_t)(n0 + sr) * 1024 + sg * 8;
  const ushort* Bb = hpT + (size_t)sr * 1024 + sg * 8;
  f32x4 acc[4][4];
#pragma unroll
  for (int i = 0; i < 4; ++i)
#pragma unroll
    for (int j = 0; j < 4; ++j) acc[i][j] = (f32x4){0.f, 0.f, 0.f, 0.f};
  uint4 ra[4], rb[4];
#pragma unroll
  for (int i = 0; i < 4; ++i) {
    ra[i] = *(const uint4*)(Ab + (size_t)i * 32 * 1024);
    rb[i] = *(const uint4*)(Bb + (size_t)i * 32 * 1024);
  }
#pragma unroll
  for (int i = 0; i < 4; ++i) {
    *(uint4*)&Al[0][(sr + 32 * i) * 72 + sg * 8] = ra[i];
    *(uint4*)&Bl[0][(sr + 32 * i) * 72 + sg * 8] = rb[i];
  }
  __syncthreads();
  for (int c = 0; c < 16; ++c) {
    int p = c & 1;
    if (c < 15) {
      int ko = (c + 1) * 64;
#pragma unroll
      for (int i = 0; i < 4; ++i) {
        ra[i] = *(const uint4*)(Ab + (size_t)i * 32 * 1024 + ko);
        rb[i] = *(const uint4*)(Bb + (size_t)i * 32 * 1024 + ko);
      }
    }
    mfma_tile128(Al[p], Bl[p], acc, wr, wc, lr, lq);
    if (c < 15) {
      int q = p ^ 1;
#pragma unroll
      for (int i = 0; i < 4; ++i) {
        *(uint4*)&Al[q][(sr + 32 * i) * 72 + sg * 8] = ra[i];
        *(uint4*)&Bl[q][(sr + 32 * i) * 72 + sg * 8] = rb[i];
      }
    }
    __syncthreads();
  }
#pragma unroll
  for (int i = 0; i < 4; ++i) {
    int n_g = n0 + wr * 64 + i * 16 + lq * 4;
#pragma unroll
    for (int j = 0; j < 4; ++j) {
      int h = wc * 64 + j * 16 + lr;
#pragma unroll
      for (int r = 0; r < 4; ++r)
        hyp[(size_t)(n_g + r) * 128 + h] = acc[i][j][r];
    }
  }
}

// ---------------------------------------------------------------------------
// k_hyp_f32: same as k_hyp_bf but stages A from fp32 Q (fallback when the
// workspace cannot hold Qbf). Converts to bf16 in the staging path.
// ---------------------------------------------------------------------------
__global__ __launch_bounds__(256) void k_hyp_f32(
    const float* __restrict__ Q, const ushort* __restrict__ hpT,
    float* __restrict__ hyp) {
  __shared__ ushort Al[2][128 * 72];
  __shared__ ushort Bl[2][128 * 72];
  int t = threadIdx.x;
  int n0 = blockIdx.x * 128;
  int wv = t >> 6, lane = t & 63;
  int wr = wv >> 1, wc = wv & 1;
  int lr = lane & 15, lq = lane >> 4;
  int ar = t >> 4, ag = t & 15;  // A staging: rows ar+16i, float4 granule ag
  int sr = t >> 3, sg = t & 7;   // B staging
  const float* Af = Q + (size_t)(n0 + ar) * 1024 + ag * 4;
  const ushort* Bb = hpT + (size_t)sr * 1024 + sg * 8;
  f32x4 acc[4][4];
#pragma unroll
  for (int i = 0; i < 4; ++i)
#pragma unroll
    for (int j = 0; j < 4; ++j) acc[i][j] = (f32x4){0.f, 0.f, 0.f, 0.f};
  float4 rf[8];
  uint4 rb[4];
#pragma unroll
  for (int i = 0; i < 8; ++i) rf[i] = *(const float4*)(Af + (size_t)i * 16 * 1024);
#pragma unroll
  for (int i = 0; i < 4; ++i) rb[i] = *(const uint4*)(Bb + (size_t)i * 32 * 1024);
#pragma unroll
  for (int i = 0; i < 8; ++i) {
    uint2 pk;
    pk.x = (uint)f2bf(rf[i].x) | ((uint)f2bf(rf[i].y) << 16);
    pk.y = (uint)f2bf(rf[i].z) | ((uint)f2bf(rf[i].w) << 16);
    *(uint2*)&Al[0][(ar + 16 * i) * 72 + ag * 4] = pk;
  }
#pragma unroll
  for (int i = 0; i < 4; ++i)
    *(uint4*)&Bl[0][(sr + 32 * i) * 72 + sg * 8] = rb[i];
  __syncthreads();
  for (int c = 0; c < 16; ++c) {
    int p = c & 1;
    if (c < 15) {
      int ko = (c + 1) * 64;
#pragma unroll
      for (int i = 0; i < 8; ++i)
        rf[i] = *(const float4*)(Af + (size_t)i * 16 * 1024 + ko);
#pragma unroll
      for (int i = 0; i < 4; ++i)
        rb[i] = *(const uint4*)(Bb + (size_t)i * 32 * 1024 + ko);
    }
    mfma_tile128(Al[p], Bl[p], acc, wr, wc, lr, lq);
    if (c < 15) {
      int q = p ^ 1;
#pragma unroll
      for (int i = 0; i < 8; ++i) {
        uint2 pk;
        pk.x = (uint)f2bf(rf[i].x) | ((uint)f2bf(rf[i].y) << 16);
        pk.y = (uint)f2bf(rf[i].z) | ((uint)f2bf(rf[i].w) << 16);
        *(uint2*)&Al[q][(ar + 16 * i) * 72 + ag * 4] = pk;
      }
#pragma unroll
      for (int i = 0; i < 4; ++i)
        *(uint4*)&Bl[q][(sr + 32 * i) * 72 + sg * 8] = rb[i];
    }
    __syncthreads();
  }
#pragma unroll
  for (int i = 0; i < 4; ++i) {
    int n_g = n0 + wr * 64 + i * 16 + lq * 4;
#pragma unroll
    for (int j = 0; j < 4; ++j) {
      int h = wc * 64 + j * 16 + lr;
#pragma unroll
      for (int r = 0; r < 4; ++r)
        hyp[(size_t)(n_g + r) * 128 + h] = acc[i][j][r];
    }
  }
}

// ---------------------------------------------------------------------------
// htmp = hp @ W_i + b_i     [1024,128]@[128,128]  (fp32, small)
// ---------------------------------------------------------------------------
__global__ __launch_bounds__(256) void k_slin(
    const float* __restrict__ A, const float* __restrict__ W,
    const float* __restrict__ bias, float* __restrict__ out) {
  __shared__ float Wl[128 * 128];
  __shared__ float Xl[32 * 128];
  int t = threadIdx.x;
  int n0 = blockIdx.x * 32;
  {
    const float4* Wg = (const float4*)W;
    float4* Wd = (float4*)Wl;
#pragma unroll
    for (int i = 0; i < 16; ++i) Wd[t + 256 * i] = Wg[t + 256 * i];
    const float4* Xg = (const float4*)(A + (size_t)n0 * 128);
    float4* Xd = (float4*)Xl;
#pragma unroll
    for (int i = 0; i < 4; ++i) Xd[t + 256 * i] = Xg[t + 256 * i];
  }
  __syncthreads();
  int ht = t & 31, nt = t >> 5;
  int h0 = ht * 4, r0 = nt * 4;
  float acc[4][4];
#pragma unroll
  for (int c = 0; c < 4; ++c) {
    float bv = bias[h0 + c];
#pragma unroll
    for (int r = 0; r < 4; ++r) acc[r][c] = bv;
  }
  for (int k = 0; k < 128; k += 4) {
    float4 xr[4], wk[4];
#pragma unroll
    for (int r = 0; r < 4; ++r) xr[r] = *(const float4*)&Xl[(r0 + r) * 128 + k];
#pragma unroll
    for (int kk = 0; kk < 4; ++kk) wk[kk] = *(const float4*)&Wl[(k + kk) * 128 + h0];
#pragma unroll
    for (int r = 0; r < 4; ++r) {
      float xs[4] = {xr[r].x, xr[r].y, xr[r].z, xr[r].w};
#pragma unroll
      for (int kk = 0; kk < 4; ++kk) {
        acc[r][0] += xs[kk] * wk[kk].x;
        acc[r][1] += xs[kk] * wk[kk].y;
        acc[r][2] += xs[kk] * wk[kk].z;
        acc[r][3] += xs[kk] * wk[kk].w;
      }
    }
  }
#pragma unroll
  for (int r = 0; r < 4; ++r) {
    *(float4*)&out[(size_t)(n0 + r0 + r) * 128 + h0] =
        make_float4(acc[r][0], acc[r][1], acc[r][2], acc[r][3]);
  }
}

// ---------------------------------------------------------------------------
// MMPN edge aggregation (tiny: 22K edges, atomics fine)
// ---------------------------------------------------------------------------
__global__ void k_edge_mmpn(
    const float* __restrict__ htmp, const float* __restrict__ hp,
    const float* __restrict__ A_val, const int* __restrict__ A_src,
    const int* __restrict__ A_dst, const float* __restrict__ imp_val,
    const int* __restrict__ imp_src, const int* __restrict__ imp_dst,
    float* __restrict__ agg) {
  long tid = (long)blockIdx.x * 256 + threadIdx.x;
  if (tid < (long)E_A * HIDE) {
    int e = (int)(tid >> 7), h = (int)(tid & 127);
    atomicAdd(&agg[(size_t)A_dst[e] * HIDE + h],
              A_val[e] * htmp[(size_t)A_src[e] * HIDE + h]);
  } else {
    long t2 = tid - (long)E_A * HIDE;
    if (t2 < (long)E_IMP * HIDE) {
      int e = (int)(t2 >> 7), h = (int)(t2 & 127);
      atomicAdd(&agg[(size_t)imp_dst[e] * HIDE + h],
                imp_val[e] * hp[(size_t)imp_src[e] * HIDE + h]);
    }
  }
}

__global__ void k_mmpn_bn(const float* __restrict__ agg, const float* __restrict__ g,
                          const float* __restrict__ b, const float* __restrict__ m,
                          const float* __restrict__ v, float* __restrict__ hp) {
  int tid = blockIdx.x * 256 + threadIdx.x;
  int h = tid & 127;
  float sc = g[h] * rsqrtf(v[h] + EPSV);
  float y = sc * (agg[tid] - m[h]) + b[h];
  hp[tid] = y >= 0.f ? y : 0.01f * y;
}

// ---------------------------------------------------------------------------
// px linear: [N,128] @ [128,256] (rowv|colv|rowq|colq)  (fp32)
// ---------------------------------------------------------------------------
__global__ __launch_bounds__(256) void k_pxlin(
    const float* __restrict__ px, const float* __restrict__ Wrv,
    const float* __restrict__ Wcv, const float* __restrict__ Wrq,
    const float* __restrict__ Wcq, const float* __restrict__ brv,
    const float* __restrict__ bcv, const float* __restrict__ brq,
    const float* __restrict__ bcq, float* __restrict__ out) {
  __shared__ float Xl[32 * 128];
  __shared__ float Wl[32 * 256];
  int t = threadIdx.x;
  int n0 = blockIdx.x * 32;
  {
    float4* Xd = (float4*)Xl;
    const float4* Xg = (const float4*)(px + (size_t)n0 * 128);
#pragma unroll
    for (int it = 0; it < 4; ++it) Xd[t + 256 * it] = Xg[t + 256 * it];
  }
  int ct = t & 63, nt = t >> 6;
  int c0 = ct * 4, r0 = nt * 8;
  float acc[8][4];
  {
    int mt = c0 >> 6, cb = c0 & 63;
    const float* bs = mt == 0 ? brv : mt == 1 ? bcv : mt == 2 ? brq : bcq;
#pragma unroll
    for (int c = 0; c < 4; ++c) {
      float bv = bs[cb + c];
#pragma unroll
      for (int r = 0; r < 8; ++r) acc[r][c] = bv;
    }
  }
  for (int kc = 0; kc < 4; ++kc) {
    int k0 = kc * 32;
    __syncthreads();
    {
#pragma unroll
      for (int it = 0; it < 8; ++it) {
        int v = t + 256 * it;
        int kk = v >> 6, cq = v & 63;
        int c = cq * 4;
        int mt = c >> 6, cb = c & 63;
        const float* Ws = mt == 0 ? Wrv : mt == 1 ? Wcv : mt == 2 ? Wrq : Wcq;
        *(float4*)&Wl[kk * 256 + c] = *(const float4*)&Ws[(size_t)(k0 + kk) * 64 + cb];
      }
    }
    __syncthreads();
    for (int k = 0; k < 32; k += 4) {
      float4 wq[4];
#pragma unroll
      for (int kk = 0; kk < 4; ++kk) wq[kk] = *(const float4*)&Wl[(k + kk) * 256 + c0];
#pragma unroll
      for (int r = 0; r < 8; ++r) {
        float4 xq = *(const float4*)&Xl[(r0 + r) * 128 + k0 + k];
        float xs[4] = {xq.x, xq.y, xq.z, xq.w};
#pragma unroll
        for (int kk = 0; kk < 4; ++kk) {
          acc[r][0] += xs[kk] * wq[kk].x;
          acc[r][1] += xs[kk] * wq[kk].y;
          acc[r][2] += xs[kk] * wq[kk].z;
          acc[r][3] += xs[kk] * wq[kk].w;
        }
      }
    }
  }
#pragma unroll
  for (int r = 0; r < 8; ++r) {
    *(float4*)&out[(size_t)(n0 + r0 + r) * 256 + c0] =
        make_float4(acc[r][0], acc[r][1], acc[r][2], acc[r][3]);
  }
}

// LayerNorm in place on lin4 cols [128,192) and [192,256). wave per row.
__global__ void k_ln(float* __restrict__ lin4) {
  int row = blockIdx.x * 4 + (threadIdx.x >> 6);
  int lane = threadIdx.x & 63;
  float* p = lin4 + (size_t)row * 256;
#pragma unroll
  for (int g = 0; g < 2; ++g) {
    float v = p[128 + g * 64 + lane];
    float s = v, s2 = v * v;
#pragma unroll
    for (int o = 32; o > 0; o >>= 1) {
      s += __shfl_xor(s, o, 64);
      s2 += __shfl_xor(s2, o, 64);
    }
    float mu = s * (1.0f / 64.0f);
    float var = s2 * (1.0f / 64.0f) - mu * mu;
    p[128 + g * 64 + lane] = (v - mu) * rsqrtf(var + EPSV);
  }
}

// ---------------------------------------------------------------------------
// CSR build: histogram -> exclusive scan -> fill
// ---------------------------------------------------------------------------
__global__ void k_hist(const int* __restrict__ src, int* __restrict__ cnt) {
  int e = blockIdx.x * 256 + threadIdx.x;
  atomicAdd(&cnt[src[e]], 1);
}

__global__ __launch_bounds__(1024) void k_scan(const int* __restrict__ cnt,
                                               int* __restrict__ off,
                                               int* __restrict__ cur) {
  __shared__ int part[1024];
  int t = threadIdx.x;
  int base = t * 64;
  int s = 0;
  for (int i = 0; i < 64; ++i) s += cnt[base + i];
  part[t] = s;
  __syncthreads();
  for (int o = 1; o < 1024; o <<= 1) {
    int v = part[t];
    int add = (t >= o) ? part[t - o] : 0;
    __syncthreads();
    part[t] = v + add;
    __syncthreads();
  }
  int run = (t > 0) ? part[t - 1] : 0;
  for (int i = 0; i < 64; ++i) {
    off[base + i] = run;
    cur[base + i] = run;
    run += cnt[base + i];
  }
  if (t == 1023) off[65536] = run;
}

__global__ void k_fill(const int* __restrict__ src, const int* __restrict__ dst,
                       int* __restrict__ cur, int* __restrict__ csr) {
  int e = blockIdx.x * 256 + threadIdx.x;
  int p = atomicAdd(&cur[src[e]], 1);
  csr[p] = dst[e];
}

// ---------------------------------------------------------------------------
// Fused segment-softmax attention gather: one wave per output node.
// ---------------------------------------------------------------------------
__global__ __launch_bounds__(256) void k_gather(
    const float* __restrict__ lin4, int qoff, int voff,
    const int* __restrict__ off, const int* __restrict__ csr_dst,
    float* __restrict__ outp, int ooff) {
  int node = blockIdx.x * 4 + (threadIdx.x >> 6);
  int l = threadIdx.x & 63;
  float qs = lin4[(size_t)node * 256 + qoff + l];
  int i0 = off[node], i1 = off[node + 1];
  float acc = 0.f, den = 0.f;
  for (int i = i0; i < i1; ++i) {
    int d = csr_dst[i];
    const float* base = lin4 + (size_t)d * 256;
    float qd = base[qoff + l];
    float vd = base[voff + l];
    float p = qs * qd;
#pragma unroll
    for (int o = 32; o > 0; o >>= 1) p += __shfl_xor(p, o, 64);
    float w = __expf(p * (1.0f / OUTW));
    den += w;
    acc += w * vd;
  }
  float r = den > 0.f ? 1.0f / den : 0.f;
  outp[(size_t)node * HIDE + ooff + l] = acc * r;
}

__global__ void k_pxbn(float* __restrict__ px, const float* __restrict__ g,
                       const float* __restrict__ b, const float* __restrict__ m,
                       const float* __restrict__ v) {
  int tid = blockIdx.x * 256 + threadIdx.x;
  int h = tid & 127;
  float x = px[tid];
  float sc = g[h] * rsqrtf(v[h] + EPSV);
  float y = sc * (x - m[h]) + b[h];
  px[tid] = y >= 0.f ? y : 0.01f * y;
}

// final: out = softmax((hyp+px) @ final_w + final_b)
__global__ __launch_bounds__(256) void k_final(
    const float* __restrict__ hyp, const float* __restrict__ px,
    const float* __restrict__ W, const float* __restrict__ b,
    float* __restrict__ out) {
  __shared__ float Wl[128 * 16];
  __shared__ float rl[16 * 129];
  int t = threadIdx.x;
  int n0 = blockIdx.x * 16;
#pragma unroll
  for (int i = 0; i < 8; ++i) Wl[t + 256 * i] = W[t + 256 * i];
#pragma unroll
  for (int i = 0; i < 8; ++i) {
    int v = t + 256 * i;
    int r = v >> 7, c = v & 127;
    rl[r * 129 + c] = hyp[(size_t)(n0 + r) * 128 + c] + px[(size_t)(n0 + r) * 128 + c];
  }
  __syncthreads();
  int r = t >> 4, cls = t & 15;
  float acc = b[cls];
  for (int k = 0; k < 128; ++k) acc += rl[r * 129 + k] * Wl[k * 16 + cls];
  float mx = acc;
#pragma unroll
  for (int o = 8; o > 0; o >>= 1) mx = fmaxf(mx, __shfl_xor(mx, o, 16));
  float e = expf(acc - mx), s = e;
#pragma unroll
  for (int o = 8; o > 0; o >>= 1) s += __shfl_xor(s, o, 16);
  out[(size_t)(n0 + r) * 16 + cls] = e / s;
}

// ---------------------------------------------------------------------------
extern "C" void kernel_launch(void* const* d_in, const int* in_sizes, int n_in,
                              void* d_out, int out_size, void* d_ws, size_t ws_size,
                              hipStream_t stream) {
  const float* x        = (const float*)d_in[0];
  const float* Q        = (const float*)d_in[1];
  const float* prelin_w = (const float*)d_in[2];
  const float* prelin_b = (const float*)d_in[3];
  const float* bn0_g    = (const float*)d_in[4];
  const float* bn0_b    = (const float*)d_in[5];
  const float* bn0_m    = (const float*)d_in[6];
  const float* bn0_v    = (const float*)d_in[7];
  const float* mmpn_w   = (const float*)d_in[8];
  const float* mmpn_b   = (const float*)d_in[9];
  const float* mmpn_bn_g= (const float*)d_in[10];
  const float* mmpn_bn_b= (const float*)d_in[11];
  const float* mmpn_bn_m= (const float*)d_in[12];
  const float* mmpn_bn_v= (const float*)d_in[13];
  const float* A_val    = (const float*)d_in[14];
  const float* imp_val  = (const float*)d_in[15];
  const float* px_rowv_w= (const float*)d_in[16];
  const float* px_rowv_b= (const float*)d_in[17];
  const float* px_colv_w= (const float*)d_in[18];
  const float* px_colv_b= (const float*)d_in[19];
  const float* px_rowq_w= (const float*)d_in[20];
  const float* px_rowq_b= (const float*)d_in[21];
  const float* px_colq_w= (const float*)d_in[22];
  const float* px_colq_b= (const float*)d_in[23];
  const float* px_bn_g  = (const float*)d_in[24];
  const float* px_bn_b  = (const float*)d_in[25];
  const float* px_bn_m  = (const float*)d_in[26];
  const float* px_bn_v  = (const float*)d_in[27];
  const float* final_w  = (const float*)d_in[28];
  const float* final_b  = (const float*)d_in[29];
  const int* A_src   = (const int*)d_in[30];
  const int* A_dst   = (const int*)d_in[31];
  const int* imp_src = (const int*)d_in[32];
  const int* imp_dst = (const int*)d_in[33];
  const int* row_src = (const int*)d_in[34];
  const int* row_dst = (const int*)d_in[35];
  const int* col_src = (const int*)d_in[36];
  const int* col_dst = (const int*)d_in[37];
  float* out = (float*)d_out;

  float* ws = (float*)d_ws;
  float* x0px = ws; ws += (size_t)N_PIX * HIDE;          // 8.4M fp32
  float* hyp  = ws; ws += (size_t)N_PIX * HIDE;          // 8.4M fp32 (aliases hp_part)
  float* hp_part = hyp;                                   // live only hpu->hpred
  float* big  = ws; ws += (size_t)32 * 1024 * 1024;       // 128 MiB region
  ushort* Qt  = (ushort*)big;                              // phase 1: Qt bf16 [1024][65536]
  float* lin4 = big;                                       // phase 2: lin4 [N][256]
  int* off_row = (int*)(big + (size_t)N_PIX * 256);
  int* off_col = off_row + 65537;
  int* csr_row = off_col + 65537;
  int* csr_col = csr_row + E_PX;
  ushort* x0T = (ushort*)ws; ws += (size_t)HIDE * N_PIX / 2;  // bf16 [128][65536]
  ushort* hpT = (ushort*)ws; ws += (size_t)HIDE * S_SP / 2;   // bf16 [128][1024]
  float* csum = ws; ws += S_SP;
  float* hp   = ws; ws += (size_t)S_SP * HIDE;
  float* htmp = ws; ws += (size_t)S_SP * HIDE;   // reused as cur_row/cur_col
  float* agg  = ws; ws += (size_t)S_SP * HIDE;   // reused as cnt_row/cnt_col

  // Optional Qbf bf16 [N][1024] (row-major) if workspace allows (+128 MiB):
  // removes the fp32 Q re-read in k_hyp.
  size_t used = (size_t)((char*)ws - (char*)d_ws);
  ushort* Qbf = nullptr;
  if (used + (size_t)N_PIX * S_SP * sizeof(ushort) <= ws_size)
    Qbf = (ushort*)ws;

  int* cnt_row = (int*)agg;
  int* cnt_col = (int*)agg + 65536;
  int* cur_row = (int*)htmp;
  int* cur_col = (int*)htmp + 65536;

  hipMemsetAsync(csum, 0, S_SP * sizeof(float), stream);

  k_cast<<<4096, 256, 0, stream>>>(Q, Qt, csum, Qbf);
  k_x0<<<N_PIX / 32, 256, 0, stream>>>(x, prelin_w, prelin_b, bn0_g, bn0_b, bn0_m,
                                       bn0_v, x0px);
  k_xT<<<N_PIX / 256, 256, 0, stream>>>(x0px, x0T);
  k_hpu2<<<512, 256, 0, stream>>>(Qt, x0T, hp_part);
  k_hpred<<<S_SP * HIDE / 256, 256, 0, stream>>>(hp_part, csum, hp);

  for (int i = 0; i < 5; ++i) {
    k_slin<<<S_SP / 32, 256, 0, stream>>>(hp, mmpn_w + (size_t)i * HIDE * HIDE,
                                          mmpn_b + i * HIDE, htmp);
    hipMemsetAsync(agg, 0, (size_t)S_SP * HIDE * sizeof(float), stream);
    k_edge_mmpn<<<(E_A + E_IMP) * HIDE / 256, 256, 0, stream>>>(
        htmp, hp, A_val, A_src, A_dst, imp_val, imp_src, imp_dst, agg);
    k_mmpn_bn<<<S_SP * HIDE / 256, 256, 0, stream>>>(
        agg, mmpn_bn_g + i * HIDE, mmpn_bn_b + i * HIDE, mmpn_bn_m + i * HIDE,
        mmpn_bn_v + i * HIDE, hp);
  }

  k_hpT<<<S_SP / 256, 256, 0, stream>>>(hp, hpT);
  if (Qbf)
    k_hyp_bf<<<N_PIX / 128, 256, 0, stream>>>(Qbf, hpT, hyp);
  else
    k_hyp_f32<<<N_PIX / 128, 256, 0, stream>>>(Q, hpT, hyp);

  // ---- CSR build (Qt region now reusable; cnt/cur alias agg/htmp) ----
  hipMemsetAsync(cnt_row, 0, 2 * 65536 * sizeof(int), stream);
  k_hist<<<E_PX / 256, 256, 0, stream>>>(row_src, cnt_row);
  k_hist<<<E_PX / 256, 256, 0, stream>>>(col_src, cnt_col);
  k_scan<<<1, 1024, 0, stream>>>(cnt_row, off_row, cur_row);
  k_scan<<<1, 1024, 0, stream>>>(cnt_col, off_col, cur_col);
  k_fill<<<E_PX / 256, 256, 0, stream>>>(row_src, row_dst, cur_row, csr_row);
  k_fill<<<E_PX / 256, 256, 0, stream>>>(col_src, col_dst, cur_col, csr_col);

  for (int j = 0; j < 2; ++j) {
    k_pxlin<<<N_PIX / 32, 256, 0, stream>>>(
        x0px, px_rowv_w + j * 8192, px_colv_w + j * 8192, px_rowq_w + j * 8192,
        px_colq_w + j * 8192, px_rowv_b + j * 64, px_colv_b + j * 64,
        px_rowq_b + j * 64, px_colq_b + j * 64, lin4);
    k_ln<<<N_PIX / 4, 256, 0, stream>>>(lin4);
    k_gather<<<N_PIX / 4, 256, 0, stream>>>(lin4, 128, 0, off_row, csr_row, x0px, 0);
    k_gather<<<N_PIX / 4, 256, 0, stream>>>(lin4, 192, 64, off_col, csr_col, x0px, 64);
    k_pxbn<<<N_PIX * HIDE / 256, 256, 0, stream>>>(x0px, px_bn_g + j * HIDE,
                                                   px_bn_b + j * HIDE,
                                                   px_bn_m + j * HIDE,
                                                   px_bn_v + j * HIDE);
  }

  k_final<<<N_PIX / 16, 256, 0, stream>>>(hyp, x0px, final_w, final_b, out);
}

// Round 2
// 1635.253 us; speedup vs baseline: 1.1870x; 1.1193x over previous
//
#include <hip/hip_runtime.h>
#include <math.h>

#define N_PIX 65536
#define S_SP  1024
#define C_IN  128
#define HIDE  128
#define OUTW  64
#define NCLS  16
#define E_A   16384
#define E_IMP 6144
#define E_PX  1048576
#define EPSV  1e-5f

typedef __attribute__((ext_vector_type(4))) float f32x4;
typedef __attribute__((ext_vector_type(8))) short bf16x8;

__device__ inline ushort f2bf(float f) {
  uint u = __builtin_bit_cast(uint, f);
  uint r = (u + 0x7FFFu + ((u >> 16) & 1u)) >> 16;
  return (ushort)r;
}
__device__ inline float bf2f(uint u) {
  return __builtin_bit_cast(float, u << 16);
}

// ---------------------------------------------------------------------------
// x0 = BN0(x @ prelin_w + prelin_b)       [N,128] @ [128,128]  (fp32)
// ---------------------------------------------------------------------------
__global__ __launch_bounds__(256) void k_x0(
    const float* __restrict__ x, const float* __restrict__ W,
    const float* __restrict__ bias, const float* __restrict__ g,
    const float* __restrict__ bb, const float* __restrict__ m,
    const float* __restrict__ vv, float* __restrict__ out) {
  __shared__ float Wl[128 * 128];
  __shared__ float Xl[32 * 128];
  int t = threadIdx.x;
  int n0 = blockIdx.x * 32;
  {
    const float4* Wg = (const float4*)W;
    float4* Wd = (float4*)Wl;
#pragma unroll
    for (int i = 0; i < 16; ++i) Wd[t + 256 * i] = Wg[t + 256 * i];
    const float4* Xg = (const float4*)(x + (size_t)n0 * 128);
    float4* Xd = (float4*)Xl;
#pragma unroll
    for (int i = 0; i < 4; ++i) Xd[t + 256 * i] = Xg[t + 256 * i];
  }
  __syncthreads();
  int ht = t & 31, nt = t >> 5;
  int h0 = ht * 4, r0 = nt * 4;
  float acc[4][4];
#pragma unroll
  for (int c = 0; c < 4; ++c) {
    float bv = bias[h0 + c];
#pragma unroll
    for (int r = 0; r < 4; ++r) acc[r][c] = bv;
  }
  for (int k = 0; k < 128; k += 4) {
    float4 xr[4], wk[4];
#pragma unroll
    for (int r = 0; r < 4; ++r) xr[r] = *(const float4*)&Xl[(r0 + r) * 128 + k];
#pragma unroll
    for (int kk = 0; kk < 4; ++kk) wk[kk] = *(const float4*)&Wl[(k + kk) * 128 + h0];
#pragma unroll
    for (int r = 0; r < 4; ++r) {
      float xs[4] = {xr[r].x, xr[r].y, xr[r].z, xr[r].w};
#pragma unroll
      for (int kk = 0; kk < 4; ++kk) {
        acc[r][0] += xs[kk] * wk[kk].x;
        acc[r][1] += xs[kk] * wk[kk].y;
        acc[r][2] += xs[kk] * wk[kk].z;
        acc[r][3] += xs[kk] * wk[kk].w;
      }
    }
  }
#pragma unroll
  for (int c = 0; c < 4; ++c) {
    int h = h0 + c;
    float sc = g[h] * rsqrtf(vv[h] + EPSV);
    float mb = m[h], bo = bb[h];
#pragma unroll
    for (int r = 0; r < 4; ++r) acc[r][c] = sc * (acc[r][c] - mb) + bo;
  }
#pragma unroll
  for (int r = 0; r < 4; ++r) {
    *(float4*)&out[(size_t)(n0 + r0 + r) * 128 + h0] =
        make_float4(acc[r][0], acc[r][1], acc[r][2], acc[r][3]);
  }
}

// ---------------------------------------------------------------------------
// k_cast: Q fp32 [N,1024] -> Qt bf16 [1024][N] + csum[s] (exact fp32 col sums)
// Optionally also emits Qbf bf16 [N][1024] (row-major) for k_hyp_bf.
// ---------------------------------------------------------------------------
__global__ __launch_bounds__(256) void k_cast(
    const float* __restrict__ Q, ushort* __restrict__ Qt,
    float* __restrict__ csum, ushort* __restrict__ Qbf) {
  __shared__ ushort Ot[64 * 258];  // [s][n] pad 2
  __shared__ float Cs[64];
  int t = threadIdx.x;
  int nt = blockIdx.x & 255, st = blockIdx.x >> 8;
  int n0 = nt * 256, s0 = st * 64;
  int lr = t & 15, lg = t >> 4;
  if (t < 64) Cs[t] = 0.f;
  __syncthreads();
  float sums[4] = {0.f, 0.f, 0.f, 0.f};
#pragma unroll
  for (int nb = 0; nb < 4; ++nb) {
    ushort hh[4][4];
#pragma unroll
    for (int u = 0; u < 4; ++u) {
      int n = n0 + nb * 64 + lg * 4 + u;
      float4 q = *(const float4*)&Q[(size_t)n * 1024 + s0 + lr * 4];
      sums[0] += q.x; sums[1] += q.y; sums[2] += q.z; sums[3] += q.w;
      hh[u][0] = f2bf(q.x); hh[u][1] = f2bf(q.y);
      hh[u][2] = f2bf(q.z); hh[u][3] = f2bf(q.w);
      if (Qbf) {
        uint2 w;
        w.x = (uint)hh[u][0] | ((uint)hh[u][1] << 16);
        w.y = (uint)hh[u][2] | ((uint)hh[u][3] << 16);
        *(uint2*)&Qbf[(size_t)n * 1024 + s0 + lr * 4] = w;
      }
    }
#pragma unroll
    for (int v = 0; v < 4; ++v) {
      uint lo = (uint)hh[0][v] | ((uint)hh[1][v] << 16);
      uint hi = (uint)hh[2][v] | ((uint)hh[3][v] << 16);
      ushort* p = &Ot[(lr * 4 + v) * 258 + nb * 64 + lg * 4];
      *(uint*)p = lo;
      *(uint*)(p + 2) = hi;
    }
  }
#pragma unroll
  for (int v = 0; v < 4; ++v) atomicAdd(&Cs[lr * 4 + v], sums[v]);
  __syncthreads();
  if (t < 64) atomicAdd(&csum[s0 + t], Cs[t]);
#pragma unroll
  for (int i = 0; i < 16; ++i) {
    int v2 = i * 256 + t;
    int s_loc = v2 >> 6, nq = v2 & 63;
    const ushort* p = &Ot[s_loc * 258 + nq * 4];
    uint2 o;
    o.x = *(const uint*)p;
    o.y = *(const uint*)(p + 2);
    *(uint2*)&Qt[(size_t)(s0 + s_loc) * 65536 + n0 + nq * 4] = o;
  }
}

// ---------------------------------------------------------------------------
// k_xT: x0 fp32 [N,128] -> x0T bf16 [128][N]
// ---------------------------------------------------------------------------
__global__ __launch_bounds__(256) void k_xT(
    const float* __restrict__ x0, ushort* __restrict__ x0T) {
  __shared__ ushort Ot[128 * 258];  // 66 KB
  int t = threadIdx.x;
  int n0 = blockIdx.x * 256;
  int lr = t & 31, lg = t >> 5;
#pragma unroll
  for (int nb = 0; nb < 8; ++nb) {
    ushort hh[4][4];
#pragma unroll
    for (int u = 0; u < 4; ++u) {
      int n = n0 + nb * 32 + lg * 4 + u;
      float4 q = *(const float4*)&x0[(size_t)n * 128 + lr * 4];
      hh[u][0] = f2bf(q.x); hh[u][1] = f2bf(q.y);
      hh[u][2] = f2bf(q.z); hh[u][3] = f2bf(q.w);
    }
#pragma unroll
    for (int v = 0; v < 4; ++v) {
      uint lo = (uint)hh[0][v] | ((uint)hh[1][v] << 16);
      uint hi = (uint)hh[2][v] | ((uint)hh[3][v] << 16);
      ushort* p = &Ot[(lr * 4 + v) * 258 + nb * 32 + lg * 4];
      *(uint*)p = lo;
      *(uint*)(p + 2) = hi;
    }
  }
  __syncthreads();
#pragma unroll
  for (int i = 0; i < 32; ++i) {
    int v2 = i * 256 + t;
    int h = v2 >> 6, nq = v2 & 63;
    const ushort* p = &Ot[h * 258 + nq * 4];
    uint2 o;
    o.x = *(const uint*)p;
    o.y = *(const uint*)(p + 2);
    *(uint2*)&x0T[(size_t)h * 65536 + n0 + nq * 4] = o;
  }
}

// ---------------------------------------------------------------------------
// k_hpT: hp fp32 [1024][128] -> hpT bf16 [128][1024]
// ---------------------------------------------------------------------------
__global__ __launch_bounds__(256) void k_hpT(
    const float* __restrict__ hp, ushort* __restrict__ hpT) {
  __shared__ ushort Ot[128 * 258];
  int t = threadIdx.x;
  int s0 = blockIdx.x * 256;
  int lr = t & 31, lg = t >> 5;
#pragma unroll
  for (int sb = 0; sb < 8; ++sb) {
    ushort hh[4][4];
#pragma unroll
    for (int u = 0; u < 4; ++u) {
      int s = s0 + sb * 32 + lg * 4 + u;
      float4 q = *(const float4*)&hp[(size_t)s * 128 + lr * 4];
      hh[u][0] = f2bf(q.x); hh[u][1] = f2bf(q.y);
      hh[u][2] = f2bf(q.z); hh[u][3] = f2bf(q.w);
    }
#pragma unroll
    for (int v = 0; v < 4; ++v) {
      uint lo = (uint)hh[0][v] | ((uint)hh[1][v] << 16);
      uint hi = (uint)hh[2][v] | ((uint)hh[3][v] << 16);
      ushort* p = &Ot[(lr * 4 + v) * 258 + sb * 32 + lg * 4];
      *(uint*)p = lo;
      *(uint*)(p + 2) = hi;
    }
  }
  __syncthreads();
#pragma unroll
  for (int i = 0; i < 32; ++i) {
    int v2 = i * 256 + t;
    int h = v2 >> 6, sq = v2 & 63;
    const ushort* p = &Ot[h * 258 + sq * 4];
    uint2 o;
    o.x = *(const uint*)p;
    o.y = *(const uint*)(p + 2);
    *(uint2*)&hpT[(size_t)h * 1024 + s0 + sq * 4] = o;
  }
}

// ---------------------------------------------------------------------------
// Shared MFMA core for the 128x128-out pipelined GEMM tiles.
// ---------------------------------------------------------------------------
__device__ __forceinline__ void mfma_tile128(const ushort* Al, const ushort* Bl,
                                             f32x4 acc[4][4], int wr, int wc,
                                             int lr, int lq) {
#pragma unroll
  for (int kh = 0; kh < 2; ++kh) {
    bf16x8 af[4], bf[4];
#pragma unroll
    for (int i = 0; i < 4; ++i)
      af[i] = *(const bf16x8*)&Al[(wr * 64 + i * 16 + lr) * 72 + kh * 32 + lq * 8];
#pragma unroll
    for (int j = 0; j < 4; ++j)
      bf[j] = *(const bf16x8*)&Bl[(wc * 64 + j * 16 + lr) * 72 + kh * 32 + lq * 8];
#pragma unroll
    for (int i = 0; i < 4; ++i)
#pragma unroll
      for (int j = 0; j < 4; ++j)
        acc[i][j] = __builtin_amdgcn_mfma_f32_16x16x32_bf16(af[i], bf[j],
                                                            acc[i][j], 0, 0, 0);
  }
}

// ---------------------------------------------------------------------------
// k_hpu2: hp_part[kb][s][h] = Qt[s-tile][n-chunk] . x0T[h][n-chunk]^T
// ---------------------------------------------------------------------------
__global__ __launch_bounds__(256) void k_hpu2(
    const ushort* __restrict__ Qt, const ushort* __restrict__ x0T,
    float* __restrict__ hp_part) {
  __shared__ ushort Al[2][128 * 72];
  __shared__ ushort Bl[2][128 * 72];
  int t = threadIdx.x;
  int st = blockIdx.x & 7, kb = blockIdx.x >> 3;
  int s0 = st * 128;
  int wv = t >> 6, lane = t & 63;
  int wr = wv >> 1, wc = wv & 1;
  int lr = lane & 15, lq = lane >> 4;
  int sr = t >> 3, sg = t & 7;
  const ushort* Ab = Qt + (size_t)(s0 + sr) * 65536 + (size_t)kb * 1024 + sg * 8;
  const ushort* Bb = x0T + (size_t)sr * 65536 + (size_t)kb * 1024 + sg * 8;
  f32x4 acc[4][4];
#pragma unroll
  for (int i = 0; i < 4; ++i)
#pragma unroll
    for (int j = 0; j < 4; ++j) acc[i][j] = (f32x4){0.f, 0.f, 0.f, 0.f};
  uint4 ra[4], rb[4];
#pragma unroll
  for (int i = 0; i < 4; ++i) {
    ra[i] = *(const uint4*)(Ab + (size_t)i * 32 * 65536);
    rb[i] = *(const uint4*)(Bb + (size_t)i * 32 * 65536);
  }
#pragma unroll
  for (int i = 0; i < 4; ++i) {
    *(uint4*)&Al[0][(sr + 32 * i) * 72 + sg * 8] = ra[i];
    *(uint4*)&Bl[0][(sr + 32 * i) * 72 + sg * 8] = rb[i];
  }
  __syncthreads();
  for (int c = 0; c < 16; ++c) {
    int p = c & 1;
    if (c < 15) {
      int ko = (c + 1) * 64;
#pragma unroll
      for (int i = 0; i < 4; ++i) {
        ra[i] = *(const uint4*)(Ab + (size_t)i * 32 * 65536 + ko);
        rb[i] = *(const uint4*)(Bb + (size_t)i * 32 * 65536 + ko);
      }
    }
    mfma_tile128(Al[p], Bl[p], acc, wr, wc, lr, lq);
    if (c < 15) {
      int q = p ^ 1;
#pragma unroll
      for (int i = 0; i < 4; ++i) {
        *(uint4*)&Al[q][(sr + 32 * i) * 72 + sg * 8] = ra[i];
        *(uint4*)&Bl[q][(sr + 32 * i) * 72 + sg * 8] = rb[i];
      }
    }
    __syncthreads();
  }
  float* outp = hp_part + (size_t)kb * 131072;
#pragma unroll
  for (int i = 0; i < 4; ++i) {
    int s_g = s0 + wr * 64 + i * 16 + lq * 4;
#pragma unroll
    for (int j = 0; j < 4; ++j) {
      int h = wc * 64 + j * 16 + lr;
#pragma unroll
      for (int r = 0; r < 4; ++r)
        outp[(size_t)(s_g + r) * 128 + h] = acc[i][j][r];
    }
  }
}

__global__ void k_hpred(const float* __restrict__ part,
                        const float* __restrict__ csum, float* __restrict__ hp) {
  int tid = blockIdx.x * 256 + threadIdx.x;
  float s = 0.f;
  for (int kb = 0; kb < 64; ++kb) s += part[(size_t)kb * 131072 + tid];
  hp[tid] = s / csum[tid >> 7];
}

// ---------------------------------------------------------------------------
// k_hyp_bf: hyp[n][h] = Qbf[n][s] . hpT[h][s]^T   (A pre-cast bf16)
// ---------------------------------------------------------------------------
__global__ __launch_bounds__(256) void k_hyp_bf(
    const ushort* __restrict__ Qbf, const ushort* __restrict__ hpT,
    float* __restrict__ hyp) {
  __shared__ ushort Al[2][128 * 72];
  __shared__ ushort Bl[2][128 * 72];
  int t = threadIdx.x;
  int n0 = blockIdx.x * 128;
  int wv = t >> 6, lane = t & 63;
  int wr = wv >> 1, wc = wv & 1;
  int lr = lane & 15, lq = lane >> 4;
  int sr = t >> 3, sg = t & 7;
  const ushort* Ab = Qbf + (size_t)(n0 + sr) * 1024 + sg * 8;
  const ushort* Bb = hpT + (size_t)sr * 1024 + sg * 8;
  f32x4 acc[4][4];
#pragma unroll
  for (int i = 0; i < 4; ++i)
#pragma unroll
    for (int j = 0; j < 4; ++j) acc[i][j] = (f32x4){0.f, 0.f, 0.f, 0.f};
  uint4 ra[4], rb[4];
#pragma unroll
  for (int i = 0; i < 4; ++i) {
    ra[i] = *(const uint4*)(Ab + (size_t)i * 32 * 1024);
    rb[i] = *(const uint4*)(Bb + (size_t)i * 32 * 1024);
  }
#pragma unroll
  for (int i = 0; i < 4; ++i) {
    *(uint4*)&Al[0][(sr + 32 * i) * 72 + sg * 8] = ra[i];
    *(uint4*)&Bl[0][(sr + 32 * i) * 72 + sg * 8] = rb[i];
  }
  __syncthreads();
  for (int c = 0; c < 16; ++c) {
    int p = c & 1;
    if (c < 15) {
      int ko = (c + 1) * 64;
#pragma unroll
      for (int i = 0; i < 4; ++i) {
        ra[i] = *(const uint4*)(Ab + (size_t)i * 32 * 1024 + ko);
        rb[i] = *(const uint4*)(Bb + (size_t)i * 32 * 1024 + ko);
      }
    }
    mfma_tile128(Al[p], Bl[p], acc, wr, wc, lr, lq);
    if (c < 15) {
      int q = p ^ 1;
#pragma unroll
      for (int i = 0; i < 4; ++i) {
        *(uint4*)&Al[q][(sr + 32 * i) * 72 + sg * 8] = ra[i];
        *(uint4*)&Bl[q][(sr + 32 * i) * 72 + sg * 8] = rb[i];
      }
    }
    __syncthreads();
  }
#pragma unroll
  for (int i = 0; i < 4; ++i) {
    int n_g = n0 + wr * 64 + i * 16 + lq * 4;
#pragma unroll
    for (int j = 0; j < 4; ++j) {
      int h = wc * 64 + j * 16 + lr;
#pragma unroll
      for (int r = 0; r < 4; ++r)
        hyp[(size_t)(n_g + r) * 128 + h] = acc[i][j][r];
    }
  }
}

// ---------------------------------------------------------------------------
// k_hyp_f32: fallback (stages A from fp32 Q, converts in staging path)
// ---------------------------------------------------------------------------
__global__ __launch_bounds__(256) void k_hyp_f32(
    const float* __restrict__ Q, const ushort* __restrict__ hpT,
    float* __restrict__ hyp) {
  __shared__ ushort Al[2][128 * 72];
  __shared__ ushort Bl[2][128 * 72];
  int t = threadIdx.x;
  int n0 = blockIdx.x * 128;
  int wv = t >> 6, lane = t & 63;
  int wr = wv >> 1, wc = wv & 1;
  int lr = lane & 15, lq = lane >> 4;
  int ar = t >> 4, ag = t & 15;
  int sr = t >> 3, sg = t & 7;
  const float* Af = Q + (size_t)(n0 + ar) * 1024 + ag * 4;
  const ushort* Bb = hpT + (size_t)sr * 1024 + sg * 8;
  f32x4 acc[4][4];
#pragma unroll
  for (int i = 0; i < 4; ++i)
#pragma unroll
    for (int j = 0; j < 4; ++j) acc[i][j] = (f32x4){0.f, 0.f, 0.f, 0.f};
  float4 rf[8];
  uint4 rb[4];
#pragma unroll
  for (int i = 0; i < 8; ++i) rf[i] = *(const float4*)(Af + (size_t)i * 16 * 1024);
#pragma unroll
  for (int i = 0; i < 4; ++i) rb[i] = *(const uint4*)(Bb + (size_t)i * 32 * 1024);
#pragma unroll
  for (int i = 0; i < 8; ++i) {
    uint2 pk;
    pk.x = (uint)f2bf(rf[i].x) | ((uint)f2bf(rf[i].y) << 16);
    pk.y = (uint)f2bf(rf[i].z) | ((uint)f2bf(rf[i].w) << 16);
    *(uint2*)&Al[0][(ar + 16 * i) * 72 + ag * 4] = pk;
  }
#pragma unroll
  for (int i = 0; i < 4; ++i)
    *(uint4*)&Bl[0][(sr + 32 * i) * 72 + sg * 8] = rb[i];
  __syncthreads();
  for (int c = 0; c < 16; ++c) {
    int p = c & 1;
    if (c < 15) {
      int ko = (c + 1) * 64;
#pragma unroll
      for (int i = 0; i < 8; ++i)
        rf[i] = *(const float4*)(Af + (size_t)i * 16 * 1024 + ko);
#pragma unroll
      for (int i = 0; i < 4; ++i)
        rb[i] = *(const uint4*)(Bb + (size_t)i * 32 * 1024 + ko);
    }
    mfma_tile128(Al[p], Bl[p], acc, wr, wc, lr, lq);
    if (c < 15) {
      int q = p ^ 1;
#pragma unroll
      for (int i = 0; i < 8; ++i) {
        uint2 pk;
        pk.x = (uint)f2bf(rf[i].x) | ((uint)f2bf(rf[i].y) << 16);
        pk.y = (uint)f2bf(rf[i].z) | ((uint)f2bf(rf[i].w) << 16);
        *(uint2*)&Al[q][(ar + 16 * i) * 72 + ag * 4] = pk;
      }
#pragma unroll
      for (int i = 0; i < 4; ++i)
        *(uint4*)&Bl[q][(sr + 32 * i) * 72 + sg * 8] = rb[i];
    }
    __syncthreads();
  }
#pragma unroll
  for (int i = 0; i < 4; ++i) {
    int n_g = n0 + wr * 64 + i * 16 + lq * 4;
#pragma unroll
    for (int j = 0; j < 4; ++j) {
      int h = wc * 64 + j * 16 + lr;
#pragma unroll
      for (int r = 0; r < 4; ++r)
        hyp[(size_t)(n_g + r) * 128 + h] = acc[i][j][r];
    }
  }
}

// ---------------------------------------------------------------------------
// htmp = hp @ W_i + b_i     [1024,128]@[128,128]  (fp32, small)
// ---------------------------------------------------------------------------
__global__ __launch_bounds__(256) void k_slin(
    const float* __restrict__ A, const float* __restrict__ W,
    const float* __restrict__ bias, float* __restrict__ out) {
  __shared__ float Wl[128 * 128];
  __shared__ float Xl[32 * 128];
  int t = threadIdx.x;
  int n0 = blockIdx.x * 32;
  {
    const float4* Wg = (const float4*)W;
    float4* Wd = (float4*)Wl;
#pragma unroll
    for (int i = 0; i < 16; ++i) Wd[t + 256 * i] = Wg[t + 256 * i];
    const float4* Xg = (const float4*)(A + (size_t)n0 * 128);
    float4* Xd = (float4*)Xl;
#pragma unroll
    for (int i = 0; i < 4; ++i) Xd[t + 256 * i] = Xg[t + 256 * i];
  }
  __syncthreads();
  int ht = t & 31, nt = t >> 5;
  int h0 = ht * 4, r0 = nt * 4;
  float acc[4][4];
#pragma unroll
  for (int c = 0; c < 4; ++c) {
    float bv = bias[h0 + c];
#pragma unroll
    for (int r = 0; r < 4; ++r) acc[r][c] = bv;
  }
  for (int k = 0; k < 128; k += 4) {
    float4 xr[4], wk[4];
#pragma unroll
    for (int r = 0; r < 4; ++r) xr[r] = *(const float4*)&Xl[(r0 + r) * 128 + k];
#pragma unroll
    for (int kk = 0; kk < 4; ++kk) wk[kk] = *(const float4*)&Wl[(k + kk) * 128 + h0];
#pragma unroll
    for (int r = 0; r < 4; ++r) {
      float xs[4] = {xr[r].x, xr[r].y, xr[r].z, xr[r].w};
#pragma unroll
      for (int kk = 0; kk < 4; ++kk) {
        acc[r][0] += xs[kk] * wk[kk].x;
        acc[r][1] += xs[kk] * wk[kk].y;
        acc[r][2] += xs[kk] * wk[kk].z;
        acc[r][3] += xs[kk] * wk[kk].w;
      }
    }
  }
#pragma unroll
  for (int r = 0; r < 4; ++r) {
    *(float4*)&out[(size_t)(n0 + r0 + r) * 128 + h0] =
        make_float4(acc[r][0], acc[r][1], acc[r][2], acc[r][3]);
  }
}

// ---------------------------------------------------------------------------
// MMPN: fused dst-CSR gather + BN + lrelu (atomic-free).
// 2 dst-rows per block (128 threads each). Reads htmp (A-edges) and hpin
// (imp-edges), writes hpout.  All data L2-resident (512 KB each).
// ---------------------------------------------------------------------------
__global__ __launch_bounds__(256) void k_mmpn_agg(
    const float* __restrict__ htmp, const float* __restrict__ hpin,
    const int* __restrict__ offA, const int* __restrict__ srcA,
    const float* __restrict__ valA, const int* __restrict__ offI,
    const int* __restrict__ srcI, const float* __restrict__ valI,
    const float* __restrict__ g, const float* __restrict__ b,
    const float* __restrict__ m, const float* __restrict__ v,
    float* __restrict__ hpout) {
  int s = blockIdx.x * 2 + (threadIdx.x >> 7);
  int h = threadIdx.x & 127;
  float acc = 0.f;
  int a0 = offA[s], a1 = offA[s + 1];
  for (int i = a0; i < a1; ++i)
    acc += valA[i] * htmp[(size_t)srcA[i] * 128 + h];
  int b0 = offI[s], b1 = offI[s + 1];
  for (int i = b0; i < b1; ++i)
    acc += valI[i] * hpin[(size_t)srcI[i] * 128 + h];
  float sc = g[h] * rsqrtf(v[h] + EPSV);
  float y = sc * (acc - m[h]) + b[h];
  hpout[(size_t)s * 128 + h] = y >= 0.f ? y : 0.01f * y;
}

// ---------------------------------------------------------------------------
// px linear: [N,128] @ [128,256] (rowv|colv|rowq|colq)  (fp32)
// ---------------------------------------------------------------------------
__global__ __launch_bounds__(256) void k_pxlin(
    const float* __restrict__ px, const float* __restrict__ Wrv,
    const float* __restrict__ Wcv, const float* __restrict__ Wrq,
    const float* __restrict__ Wcq, const float* __restrict__ brv,
    const float* __restrict__ bcv, const float* __restrict__ brq,
    const float* __restrict__ bcq, float* __restrict__ out) {
  __shared__ float Xl[32 * 128];
  __shared__ float Wl[32 * 256];
  int t = threadIdx.x;
  int n0 = blockIdx.x * 32;
  {
    float4* Xd = (float4*)Xl;
    const float4* Xg = (const float4*)(px + (size_t)n0 * 128);
#pragma unroll
    for (int it = 0; it < 4; ++it) Xd[t + 256 * it] = Xg[t + 256 * it];
  }
  int ct = t & 63, nt = t >> 6;
  int c0 = ct * 4, r0 = nt * 8;
  float acc[8][4];
  {
    int mt = c0 >> 6, cb = c0 & 63;
    const float* bs = mt == 0 ? brv : mt == 1 ? bcv : mt == 2 ? brq : bcq;
#pragma unroll
    for (int c = 0; c < 4; ++c) {
      float bv = bs[cb + c];
#pragma unroll
      for (int r = 0; r < 8; ++r) acc[r][c] = bv;
    }
  }
  for (int kc = 0; kc < 4; ++kc) {
    int k0 = kc * 32;
    __syncthreads();
    {
#pragma unroll
      for (int it = 0; it < 8; ++it) {
        int v = t + 256 * it;
        int kk = v >> 6, cq = v & 63;
        int c = cq * 4;
        int mt = c >> 6, cb = c & 63;
        const float* Ws = mt == 0 ? Wrv : mt == 1 ? Wcv : mt == 2 ? Wrq : Wcq;
        *(float4*)&Wl[kk * 256 + c] = *(const float4*)&Ws[(size_t)(k0 + kk) * 64 + cb];
      }
    }
    __syncthreads();
    for (int k = 0; k < 32; k += 4) {
      float4 wq[4];
#pragma unroll
      for (int kk = 0; kk < 4; ++kk) wq[kk] = *(const float4*)&Wl[(k + kk) * 256 + c0];
#pragma unroll
      for (int r = 0; r < 8; ++r) {
        float4 xq = *(const float4*)&Xl[(r0 + r) * 128 + k0 + k];
        float xs[4] = {xq.x, xq.y, xq.z, xq.w};
#pragma unroll
        for (int kk = 0; kk < 4; ++kk) {
          acc[r][0] += xs[kk] * wq[kk].x;
          acc[r][1] += xs[kk] * wq[kk].y;
          acc[r][2] += xs[kk] * wq[kk].z;
          acc[r][3] += xs[kk] * wq[kk].w;
        }
      }
    }
  }
#pragma unroll
  for (int r = 0; r < 8; ++r) {
    *(float4*)&out[(size_t)(n0 + r0 + r) * 256 + c0] =
        make_float4(acc[r][0], acc[r][1], acc[r][2], acc[r][3]);
  }
}

// ---------------------------------------------------------------------------
// k_pack: per row, LN the q-halves and pack (q|v) bf16 into pkrow/pkcol.
// pk record: node*64 + lane -> uint = q_l (low 16) | v_l (high 16). 256 B/node.
// ---------------------------------------------------------------------------
__global__ __launch_bounds__(256) void k_pack(
    const float* __restrict__ lin4, uint* __restrict__ pkrow,
    uint* __restrict__ pkcol) {
  int row = blockIdx.x * 4 + (threadIdx.x >> 6);
  int l = threadIdx.x & 63;
  const float* p = lin4 + (size_t)row * 256;
#pragma unroll
  for (int gsel = 0; gsel < 2; ++gsel) {
    float q = p[128 + gsel * 64 + l];
    float s = q, s2 = q * q;
#pragma unroll
    for (int o = 32; o > 0; o >>= 1) {
      s += __shfl_xor(s, o, 64);
      s2 += __shfl_xor(s2, o, 64);
    }
    float mu = s * (1.0f / 64.0f);
    float var = s2 * (1.0f / 64.0f) - mu * mu;
    float qn = (q - mu) * rsqrtf(var + EPSV);
    float vv = p[gsel * 64 + l];
    uint pkv = (uint)f2bf(qn) | ((uint)f2bf(vv) << 16);
    (gsel ? pkcol : pkrow)[(size_t)row * 64 + l] = pkv;
  }
}

// ---------------------------------------------------------------------------
// CSR build: histogram -> exclusive scan -> fill
// ---------------------------------------------------------------------------
__global__ void k_hist(const int* __restrict__ src, int* __restrict__ cnt) {
  int e = blockIdx.x * 256 + threadIdx.x;
  atomicAdd(&cnt[src[e]], 1);
}

__global__ __launch_bounds__(1024) void k_scan(const int* __restrict__ cnt,
                                               int* __restrict__ off,
                                               int* __restrict__ cur) {
  __shared__ int part[1024];
  int t = threadIdx.x;
  int base = t * 64;
  int s = 0;
  for (int i = 0; i < 64; ++i) s += cnt[base + i];
  part[t] = s;
  __syncthreads();
  for (int o = 1; o < 1024; o <<= 1) {
    int v = part[t];
    int add = (t >= o) ? part[t - o] : 0;
    __syncthreads();
    part[t] = v + add;
    __syncthreads();
  }
  int run = (t > 0) ? part[t - 1] : 0;
  for (int i = 0; i < 64; ++i) {
    off[base + i] = run;
    cur[base + i] = run;
    run += cnt[base + i];
  }
  if (t == 1023) off[65536] = run;
}

// small scan over exactly 1024 counters (for MMPN CSRs)
__global__ __launch_bounds__(1024) void k_scan_s(const int* __restrict__ cnt,
                                                 int* __restrict__ off,
                                                 int* __restrict__ cur) {
  __shared__ int part[1024];
  int t = threadIdx.x;
  int v = cnt[t];
  part[t] = v;
  __syncthreads();
  for (int o = 1; o < 1024; o <<= 1) {
    int x = part[t];
    int a = (t >= o) ? part[t - o] : 0;
    __syncthreads();
    part[t] = x + a;
    __syncthreads();
  }
  int ex = (t > 0) ? part[t - 1] : 0;
  off[t] = ex;
  cur[t] = ex;
  if (t == 1023) off[1024] = part[1023];
}

__global__ void k_fill(const int* __restrict__ src, const int* __restrict__ dst,
                       int* __restrict__ cur, int* __restrict__ csr) {
  int e = blockIdx.x * 256 + threadIdx.x;
  int p = atomicAdd(&cur[src[e]], 1);
  csr[p] = dst[e];
}

// fill with (src, val) payload, keyed by dst (for MMPN)
__global__ void k_fill_v(const int* __restrict__ dst, const int* __restrict__ src,
                         const float* __restrict__ val, int* __restrict__ cur,
                         int* __restrict__ csr_src, float* __restrict__ csr_val) {
  int e = blockIdx.x * 256 + threadIdx.x;
  int p = atomicAdd(&cur[dst[e]], 1);
  csr_src[p] = src[e];
  csr_val[p] = val[e];
}

// ---------------------------------------------------------------------------
// Fused segment-softmax attention gather over packed bf16 (q|v) records.
// One wave per node; 256 B per edge, contiguous; BN+lrelu fused in epilogue.
// ---------------------------------------------------------------------------
__global__ __launch_bounds__(256) void k_gather2(
    const uint* __restrict__ pk, const int* __restrict__ off,
    const int* __restrict__ csr, const float* __restrict__ g,
    const float* __restrict__ b, const float* __restrict__ m,
    const float* __restrict__ v, int ooff, float* __restrict__ outp) {
  int node = blockIdx.x * 4 + (threadIdx.x >> 6);
  int l = threadIdx.x & 63;
  uint rs = pk[(size_t)node * 64 + l];
  float qs = bf2f(rs & 0xffffu);
  int i0 = off[node], i1 = off[node + 1];
  float acc = 0.f, den = 0.f;
  int i = i0;
  for (; i + 2 <= i1; i += 2) {
    int d0 = csr[i], d1 = csr[i + 1];
    uint r0 = pk[(size_t)d0 * 64 + l];
    uint r1 = pk[(size_t)d1 * 64 + l];
    float p0 = qs * bf2f(r0 & 0xffffu);
    float p1 = qs * bf2f(r1 & 0xffffu);
#pragma unroll
    for (int o = 32; o > 0; o >>= 1) {
      p0 += __shfl_xor(p0, o, 64);
      p1 += __shfl_xor(p1, o, 64);
    }
    float w0 = __expf(p0 * (1.0f / OUTW));
    float w1 = __expf(p1 * (1.0f / OUTW));
    den += w0 + w1;
    acc += w0 * bf2f(r0 >> 16) + w1 * bf2f(r1 >> 16);
  }
  if (i < i1) {
    int d0 = csr[i];
    uint r0 = pk[(size_t)d0 * 64 + l];
    float p0 = qs * bf2f(r0 & 0xffffu);
#pragma unroll
    for (int o = 32; o > 0; o >>= 1) p0 += __shfl_xor(p0, o, 64);
    float w0 = __expf(p0 * (1.0f / OUTW));
    den += w0;
    acc += w0 * bf2f(r0 >> 16);
  }
  float r = den > 0.f ? 1.0f / den : 0.f;
  float val = acc * r;
  int h = ooff + l;
  float sc = g[h] * rsqrtf(v[h] + EPSV);
  float y = sc * (val - m[h]) + b[h];
  outp[(size_t)node * HIDE + h] = y >= 0.f ? y : 0.01f * y;
}

// final: out = softmax((hyp+px) @ final_w + final_b)
__global__ __launch_bounds__(256) void k_final(
    const float* __restrict__ hyp, const float* __restrict__ px,
    const float* __restrict__ W, const float* __restrict__ b,
    float* __restrict__ out) {
  __shared__ float Wl[128 * 16];
  __shared__ float rl[16 * 129];
  int t = threadIdx.x;
  int n0 = blockIdx.x * 16;
#pragma unroll
  for (int i = 0; i < 8; ++i) Wl[t + 256 * i] = W[t + 256 * i];
#pragma unroll
  for (int i = 0; i < 8; ++i) {
    int v = t + 256 * i;
    int r = v >> 7, c = v & 127;
    rl[r * 129 + c] = hyp[(size_t)(n0 + r) * 128 + c] + px[(size_t)(n0 + r) * 128 + c];
  }
  __syncthreads();
  int r = t >> 4, cls = t & 15;
  float acc = b[cls];
  for (int k = 0; k < 128; ++k) acc += rl[r * 129 + k] * Wl[k * 16 + cls];
  float mx = acc;
#pragma unroll
  for (int o = 8; o > 0; o >>= 1) mx = fmaxf(mx, __shfl_xor(mx, o, 16));
  float e = expf(acc - mx), s = e;
#pragma unroll
  for (int o = 8; o > 0; o >>= 1) s += __shfl_xor(s, o, 16);
  out[(size_t)(n0 + r) * 16 + cls] = e / s;
}

// ---------------------------------------------------------------------------
extern "C" void kernel_launch(void* const* d_in, const int* in_sizes, int n_in,
                              void* d_out, int out_size, void* d_ws, size_t ws_size,
                              hipStream_t stream) {
  const float* x        = (const float*)d_in[0];
  const float* Q        = (const float*)d_in[1];
  const float* prelin_w = (const float*)d_in[2];
  const float* prelin_b = (const float*)d_in[3];
  const float* bn0_g    = (const float*)d_in[4];
  const float* bn0_b    = (const float*)d_in[5];
  const float* bn0_m    = (const float*)d_in[6];
  const float* bn0_v    = (const float*)d_in[7];
  const float* mmpn_w   = (const float*)d_in[8];
  const float* mmpn_b   = (const float*)d_in[9];
  const float* mmpn_bn_g= (const float*)d_in[10];
  const float* mmpn_bn_b= (const float*)d_in[11];
  const float* mmpn_bn_m= (const float*)d_in[12];
  const float* mmpn_bn_v= (const float*)d_in[13];
  const float* A_val    = (const float*)d_in[14];
  const float* imp_val  = (const float*)d_in[15];
  const float* px_rowv_w= (const float*)d_in[16];
  const float* px_rowv_b= (const float*)d_in[17];
  const float* px_colv_w= (const float*)d_in[18];
  const float* px_colv_b= (const float*)d_in[19];
  const float* px_rowq_w= (const float*)d_in[20];
  const float* px_rowq_b= (const float*)d_in[21];
  const float* px_colq_w= (const float*)d_in[22];
  const float* px_colq_b= (const float*)d_in[23];
  const float* px_bn_g  = (const float*)d_in[24];
  const float* px_bn_b  = (const float*)d_in[25];
  const float* px_bn_m  = (const float*)d_in[26];
  const float* px_bn_v  = (const float*)d_in[27];
  const float* final_w  = (const float*)d_in[28];
  const float* final_b  = (const float*)d_in[29];
  const int* A_src   = (const int*)d_in[30];
  const int* A_dst   = (const int*)d_in[31];
  const int* imp_src = (const int*)d_in[32];
  const int* imp_dst = (const int*)d_in[33];
  const int* row_src = (const int*)d_in[34];
  const int* row_dst = (const int*)d_in[35];
  const int* col_src = (const int*)d_in[36];
  const int* col_dst = (const int*)d_in[37];
  float* out = (float*)d_out;

  float* ws = (float*)d_ws;
  float* x0px = ws; ws += (size_t)N_PIX * HIDE;          // 32 MB fp32
  float* hyp  = ws; ws += (size_t)N_PIX * HIDE;          // 32 MB fp32 (aliases hp_part)
  float* hp_part = hyp;                                   // live only hpu->hpred
  float* big  = ws; ws += (size_t)32 * 1024 * 1024;       // 128 MiB region
  ushort* Qt  = (ushort*)big;                              // phase 1: Qt bf16 [1024][65536]
  float* lin4 = big;                                       // phase 2: lin4 [N][256] (64 MB)
  int* off_row = (int*)(big + (size_t)N_PIX * 256);        // +64 MB
  int* off_col = off_row + 65537;
  int* csr_row = off_col + 65537;
  int* csr_col = csr_row + E_PX;                           // ends ~72.5 MB
  uint* pkrow = (uint*)(big + (size_t)20 * 1024 * 1024);   // +80 MB, 16 MB
  uint* pkcol = pkrow + (size_t)N_PIX * 64;                // +96 MB, 16 MB
  ushort* x0T = (ushort*)ws; ws += (size_t)HIDE * N_PIX / 2;  // bf16 [128][65536]
  ushort* hpT = (ushort*)ws; ws += (size_t)HIDE * S_SP / 2;   // bf16 [128][1024]
  float* csum = ws; ws += S_SP;
  float* hp   = ws; ws += (size_t)S_SP * HIDE;
  float* htmp = ws; ws += (size_t)S_SP * HIDE;   // reused as cur_row/cur_col
  float* agg  = ws; ws += (size_t)S_SP * HIDE;   // MMPN ping-pong; later cnt_row/col

  // MMPN dst-CSR arrays (tiny)
  int* offA = (int*)ws;
  int* offI = offA + 1025;
  int* cntA = offI + 1025;   // cntA,cntI contiguous for single memset
  int* cntI = cntA + 1024;
  int* curA = cntI + 1024;
  int* curI = curA + 1024;
  int* srcA = curI + 1024;
  float* valA = (float*)(srcA + E_A);
  int* srcI = (int*)(valA + E_A);
  float* valI = (float*)(srcI + E_IMP);
  ws = (float*)(valI + E_IMP);
  ws = (float*)(((uintptr_t)ws + 15) & ~(uintptr_t)15);

  // Optional Qbf bf16 [N][1024] row-major (+128 MiB): kills fp32 Q re-read.
  size_t used = (size_t)((char*)ws - (char*)d_ws);
  ushort* Qbf = nullptr;
  if (used + (size_t)N_PIX * S_SP * sizeof(ushort) <= ws_size)
    Qbf = (ushort*)ws;

  int* cnt_row = (int*)agg;
  int* cnt_col = (int*)agg + 65536;
  int* cur_row = (int*)htmp;
  int* cur_col = (int*)htmp + 65536;

  hipMemsetAsync(csum, 0, S_SP * sizeof(float), stream);
  hipMemsetAsync(cntA, 0, 2 * 1024 * sizeof(int), stream);

  // MMPN dst-CSR build (edges are tiny; once per launch)
  k_hist<<<E_A / 256, 256, 0, stream>>>(A_dst, cntA);
  k_hist<<<E_IMP / 256, 256, 0, stream>>>(imp_dst, cntI);
  k_scan_s<<<1, 1024, 0, stream>>>(cntA, offA, curA);
  k_scan_s<<<1, 1024, 0, stream>>>(cntI, offI, curI);
  k_fill_v<<<E_A / 256, 256, 0, stream>>>(A_dst, A_src, A_val, curA, srcA, valA);
  k_fill_v<<<E_IMP / 256, 256, 0, stream>>>(imp_dst, imp_src, imp_val, curI, srcI, valI);

  k_cast<<<4096, 256, 0, stream>>>(Q, Qt, csum, Qbf);
  k_x0<<<N_PIX / 32, 256, 0, stream>>>(x, prelin_w, prelin_b, bn0_g, bn0_b, bn0_m,
                                       bn0_v, x0px);
  k_xT<<<N_PIX / 256, 256, 0, stream>>>(x0px, x0T);
  k_hpu2<<<512, 256, 0, stream>>>(Qt, x0T, hp_part);
  k_hpred<<<S_SP * HIDE / 256, 256, 0, stream>>>(hp_part, csum, hp);

  {
    float* cur = hp;
    float* nxt = agg;
    for (int i = 0; i < 5; ++i) {
      k_slin<<<S_SP / 32, 256, 0, stream>>>(cur, mmpn_w + (size_t)i * HIDE * HIDE,
                                            mmpn_b + i * HIDE, htmp);
      k_mmpn_agg<<<S_SP / 2, 256, 0, stream>>>(
          htmp, cur, offA, srcA, valA, offI, srcI, valI,
          mmpn_bn_g + i * HIDE, mmpn_bn_b + i * HIDE, mmpn_bn_m + i * HIDE,
          mmpn_bn_v + i * HIDE, nxt);
      float* tmp = cur; cur = nxt; nxt = tmp;
    }
    k_hpT<<<S_SP / 256, 256, 0, stream>>>(cur, hpT);
  }
  if (Qbf)
    k_hyp_bf<<<N_PIX / 128, 256, 0, stream>>>(Qbf, hpT, hyp);
  else
    k_hyp_f32<<<N_PIX / 128, 256, 0, stream>>>(Q, hpT, hyp);

  // ---- pixel CSR build (Qt region reusable; cnt/cur alias agg/htmp) ----
  hipMemsetAsync(cnt_row, 0, 2 * 65536 * sizeof(int), stream);
  k_hist<<<E_PX / 256, 256, 0, stream>>>(row_src, cnt_row);
  k_hist<<<E_PX / 256, 256, 0, stream>>>(col_src, cnt_col);
  k_scan<<<1, 1024, 0, stream>>>(cnt_row, off_row, cur_row);
  k_scan<<<1, 1024, 0, stream>>>(cnt_col, off_col, cur_col);
  k_fill<<<E_PX / 256, 256, 0, stream>>>(row_src, row_dst, cur_row, csr_row);
  k_fill<<<E_PX / 256, 256, 0, stream>>>(col_src, col_dst, cur_col, csr_col);

  for (int j = 0; j < 2; ++j) {
    k_pxlin<<<N_PIX / 32, 256, 0, stream>>>(
        x0px, px_rowv_w + j * 8192, px_colv_w + j * 8192, px_rowq_w + j * 8192,
        px_colq_w + j * 8192, px_rowv_b + j * 64, px_colv_b + j * 64,
        px_rowq_b + j * 64, px_colq_b + j * 64, lin4);
    k_pack<<<N_PIX / 4, 256, 0, stream>>>(lin4, pkrow, pkcol);
    k_gather2<<<N_PIX / 4, 256, 0, stream>>>(
        pkrow, off_row, csr_row, px_bn_g + j * HIDE, px_bn_b + j * HIDE,
        px_bn_m + j * HIDE, px_bn_v + j * HIDE, 0, x0px);
    k_gather2<<<N_PIX / 4, 256, 0, stream>>>(
        pkcol, off_col, csr_col, px_bn_g + j * HIDE, px_bn_b + j * HIDE,
        px_bn_m + j * HIDE, px_bn_v + j * HIDE, 64, x0px);
  }

  k_final<<<N_PIX / 16, 256, 0, stream>>>(hyp, x0px, final_w, final_b, out);
}

// Round 3
// 1585.139 us; speedup vs baseline: 1.2245x; 1.0316x over previous
//
#include <hip/hip_runtime.h>
#include <math.h>

#define N_PIX 65536
#define S_SP  1024
#define C_IN  128
#define HIDE  128
#define OUTW  64
#define NCLS  16
#define E_A   16384
#define E_IMP 6144
#define E_PX  1048576
#define EPSV  1e-5f

typedef __attribute__((ext_vector_type(4))) float f32x4;
typedef __attribute__((ext_vector_type(8))) short bf16x8;

__device__ inline ushort f2bf(float f) {
  uint u = __builtin_bit_cast(uint, f);
  uint r = (u + 0x7FFFu + ((u >> 16) & 1u)) >> 16;
  return (ushort)r;
}
__device__ inline float bf2f(uint u) {
  return __builtin_bit_cast(float, u << 16);
}

// ---------------------------------------------------------------------------
// x0 = BN0(x @ prelin_w + prelin_b)       [N,128] @ [128,128]  (fp32)
// ---------------------------------------------------------------------------
__global__ __launch_bounds__(256) void k_x0(
    const float* __restrict__ x, const float* __restrict__ W,
    const float* __restrict__ bias, const float* __restrict__ g,
    const float* __restrict__ bb, const float* __restrict__ m,
    const float* __restrict__ vv, float* __restrict__ out) {
  __shared__ float Wl[128 * 128];
  __shared__ float Xl[32 * 128];
  int t = threadIdx.x;
  int n0 = blockIdx.x * 32;
  {
    const float4* Wg = (const float4*)W;
    float4* Wd = (float4*)Wl;
#pragma unroll
    for (int i = 0; i < 16; ++i) Wd[t + 256 * i] = Wg[t + 256 * i];
    const float4* Xg = (const float4*)(x + (size_t)n0 * 128);
    float4* Xd = (float4*)Xl;
#pragma unroll
    for (int i = 0; i < 4; ++i) Xd[t + 256 * i] = Xg[t + 256 * i];
  }
  __syncthreads();
  int ht = t & 31, nt = t >> 5;
  int h0 = ht * 4, r0 = nt * 4;
  float acc[4][4];
#pragma unroll
  for (int c = 0; c < 4; ++c) {
    float bv = bias[h0 + c];
#pragma unroll
    for (int r = 0; r < 4; ++r) acc[r][c] = bv;
  }
  for (int k = 0; k < 128; k += 4) {
    float4 xr[4], wk[4];
#pragma unroll
    for (int r = 0; r < 4; ++r) xr[r] = *(const float4*)&Xl[(r0 + r) * 128 + k];
#pragma unroll
    for (int kk = 0; kk < 4; ++kk) wk[kk] = *(const float4*)&Wl[(k + kk) * 128 + h0];
#pragma unroll
    for (int r = 0; r < 4; ++r) {
      float xs[4] = {xr[r].x, xr[r].y, xr[r].z, xr[r].w};
#pragma unroll
      for (int kk = 0; kk < 4; ++kk) {
        acc[r][0] += xs[kk] * wk[kk].x;
        acc[r][1] += xs[kk] * wk[kk].y;
        acc[r][2] += xs[kk] * wk[kk].z;
        acc[r][3] += xs[kk] * wk[kk].w;
      }
    }
  }
#pragma unroll
  for (int c = 0; c < 4; ++c) {
    int h = h0 + c;
    float sc = g[h] * rsqrtf(vv[h] + EPSV);
    float mb = m[h], bo = bb[h];
#pragma unroll
    for (int r = 0; r < 4; ++r) acc[r][c] = sc * (acc[r][c] - mb) + bo;
  }
#pragma unroll
  for (int r = 0; r < 4; ++r) {
    *(float4*)&out[(size_t)(n0 + r0 + r) * 128 + h0] =
        make_float4(acc[r][0], acc[r][1], acc[r][2], acc[r][3]);
  }
}

// ---------------------------------------------------------------------------
// k_cast2: pure streaming  Q fp32 [N,1024] -> Qbf bf16 [N,1024] + csum[s].
// 1024 blocks x 64 rows; each thread owns 4 fixed columns -> private fp32
// accumulators, one atomicAdd per column per block (exact fp32 partials).
// ---------------------------------------------------------------------------
__global__ __launch_bounds__(256) void k_cast2(
    const float* __restrict__ Q, ushort* __restrict__ Qbf,
    float* __restrict__ csum) {
  int t = threadIdx.x;
  int n0 = blockIdx.x * 64;
  const float* qp = Q + (size_t)n0 * 1024 + t * 4;
  ushort* op = Qbf + (size_t)n0 * 1024 + t * 4;
  float s0 = 0.f, s1 = 0.f, s2 = 0.f, s3 = 0.f;
#pragma unroll 4
  for (int u = 0; u < 64; ++u) {
    float4 q = *(const float4*)(qp + (size_t)u * 1024);
    s0 += q.x; s1 += q.y; s2 += q.z; s3 += q.w;
    uint2 w;
    w.x = (uint)f2bf(q.x) | ((uint)f2bf(q.y) << 16);
    w.y = (uint)f2bf(q.z) | ((uint)f2bf(q.w) << 16);
    *(uint2*)(op + (size_t)u * 1024) = w;
  }
  int s = t * 4;
  atomicAdd(&csum[s], s0);
  atomicAdd(&csum[s + 1], s1);
  atomicAdd(&csum[s + 2], s2);
  atomicAdd(&csum[s + 3], s3);
}

// ---------------------------------------------------------------------------
// k_xT: x0 fp32 [N,128] -> x0T bf16 [128][N]
// ---------------------------------------------------------------------------
__global__ __launch_bounds__(256) void k_xT(
    const float* __restrict__ x0, ushort* __restrict__ x0T) {
  __shared__ ushort Ot[128 * 258];  // 66 KB
  int t = threadIdx.x;
  int n0 = blockIdx.x * 256;
  int lr = t & 31, lg = t >> 5;
#pragma unroll
  for (int nb = 0; nb < 8; ++nb) {
    ushort hh[4][4];
#pragma unroll
    for (int u = 0; u < 4; ++u) {
      int n = n0 + nb * 32 + lg * 4 + u;
      float4 q = *(const float4*)&x0[(size_t)n * 128 + lr * 4];
      hh[u][0] = f2bf(q.x); hh[u][1] = f2bf(q.y);
      hh[u][2] = f2bf(q.z); hh[u][3] = f2bf(q.w);
    }
#pragma unroll
    for (int v = 0; v < 4; ++v) {
      uint lo = (uint)hh[0][v] | ((uint)hh[1][v] << 16);
      uint hi = (uint)hh[2][v] | ((uint)hh[3][v] << 16);
      ushort* p = &Ot[(lr * 4 + v) * 258 + nb * 32 + lg * 4];
      *(uint*)p = lo;
      *(uint*)(p + 2) = hi;
    }
  }
  __syncthreads();
#pragma unroll
  for (int i = 0; i < 32; ++i) {
    int v2 = i * 256 + t;
    int h = v2 >> 6, nq = v2 & 63;
    const ushort* p = &Ot[h * 258 + nq * 4];
    uint2 o;
    o.x = *(const uint*)p;
    o.y = *(const uint*)(p + 2);
    *(uint2*)&x0T[(size_t)h * 65536 + n0 + nq * 4] = o;
  }
}

// ---------------------------------------------------------------------------
// k_hpT: hp fp32 [1024][128] -> hpT bf16 [128][1024]
// ---------------------------------------------------------------------------
__global__ __launch_bounds__(256) void k_hpT(
    const float* __restrict__ hp, ushort* __restrict__ hpT) {
  __shared__ ushort Ot[128 * 258];
  int t = threadIdx.x;
  int s0 = blockIdx.x * 256;
  int lr = t & 31, lg = t >> 5;
#pragma unroll
  for (int sb = 0; sb < 8; ++sb) {
    ushort hh[4][4];
#pragma unroll
    for (int u = 0; u < 4; ++u) {
      int s = s0 + sb * 32 + lg * 4 + u;
      float4 q = *(const float4*)&hp[(size_t)s * 128 + lr * 4];
      hh[u][0] = f2bf(q.x); hh[u][1] = f2bf(q.y);
      hh[u][2] = f2bf(q.z); hh[u][3] = f2bf(q.w);
    }
#pragma unroll
    for (int v = 0; v < 4; ++v) {
      uint lo = (uint)hh[0][v] | ((uint)hh[1][v] << 16);
      uint hi = (uint)hh[2][v] | ((uint)hh[3][v] << 16);
      ushort* p = &Ot[(lr * 4 + v) * 258 + sb * 32 + lg * 4];
      *(uint*)p = lo;
      *(uint*)(p + 2) = hi;
    }
  }
  __syncthreads();
#pragma unroll
  for (int i = 0; i < 32; ++i) {
    int v2 = i * 256 + t;
    int h = v2 >> 6, sq = v2 & 63;
    const ushort* p = &Ot[h * 258 + sq * 4];
    uint2 o;
    o.x = *(const uint*)p;
    o.y = *(const uint*)(p + 2);
    *(uint2*)&hpT[(size_t)h * 1024 + s0 + sq * 4] = o;
  }
}

// ---------------------------------------------------------------------------
// Shared MFMA core for the 128x128-out pipelined GEMM tiles.
// LDS tiles [128 rows][72 shorts] (64 k + 8 pad).
// ---------------------------------------------------------------------------
__device__ __forceinline__ void mfma_tile128(const ushort* Al, const ushort* Bl,
                                             f32x4 acc[4][4], int wr, int wc,
                                             int lr, int lq) {
#pragma unroll
  for (int kh = 0; kh < 2; ++kh) {
    bf16x8 af[4], bf[4];
#pragma unroll
    for (int i = 0; i < 4; ++i)
      af[i] = *(const bf16x8*)&Al[(wr * 64 + i * 16 + lr) * 72 + kh * 32 + lq * 8];
#pragma unroll
    for (int j = 0; j < 4; ++j)
      bf[j] = *(const bf16x8*)&Bl[(wc * 64 + j * 16 + lr) * 72 + kh * 32 + lq * 8];
#pragma unroll
    for (int i = 0; i < 4; ++i)
#pragma unroll
      for (int j = 0; j < 4; ++j)
        acc[i][j] = __builtin_amdgcn_mfma_f32_16x16x32_bf16(af[i], bf[j],
                                                            acc[i][j], 0, 0, 0);
  }
}

// write one transposed s-row granule (8 n) into the A-tile from 8 uint2 rows
__device__ __forceinline__ void wrA(ushort* dst, const uint2* ra, int v) {
  uint vals[8];
#pragma unroll
  for (int u = 0; u < 8; ++u) {
    uint x = (v < 2) ? ra[u].x : ra[u].y;
    vals[u] = (v & 1) ? (x >> 16) : (x & 0xffffu);
  }
  uint4 w;
  w.x = vals[0] | (vals[1] << 16);
  w.y = vals[2] | (vals[3] << 16);
  w.z = vals[4] | (vals[5] << 16);
  w.w = vals[6] | (vals[7] << 16);
  *(uint4*)dst = w;
}

// ---------------------------------------------------------------------------
// k_hpu3: hp_part[kb][s][h] = Qbf[n-chunk][s-tile]^T . x0T[h][n-chunk]^T
// A staged from row-major Qbf via per-thread 8x4 register micro-transpose
// into the [s][72] LDS tile (write pattern 2-way bank = free).
// Block order XCD-swizzled: each XCD owns 8 kb-chunks -> its 256 KB x0T
// slices stay L2-resident (x0T HBM traffic 128 MB -> ~16 MB).
// ---------------------------------------------------------------------------
__global__ __launch_bounds__(256) void k_hpu3(
    const ushort* __restrict__ Qbf, const ushort* __restrict__ x0T,
    float* __restrict__ hp_part) {
  __shared__ ushort Al[2][128 * 72];
  __shared__ ushort Bl[2][128 * 72];
  int t = threadIdx.x;
  int p0 = blockIdx.x;
  int xcd = p0 & 7, ii = p0 >> 3;
  int kb = xcd * 8 + (ii & 7);   // kb -> fixed XCD (kb>>3)
  int st = ii >> 3;
  int s0 = st * 128;
  int n_base = kb * 1024;
  int wv = t >> 6, lane = t & 63;
  int wr = wv >> 1, wc = wv & 1;
  int lr = lane & 15, lq = lane >> 4;
  int n8 = t & 7, s4 = t >> 3;   // A staging: n-granule of 8, s-group of 4
  int sr = t >> 3, sg = t & 7;   // B staging
  const ushort* Ab = Qbf + (size_t)(n_base + n8 * 8) * 1024 + s0 + s4 * 4;
  const ushort* Bb = x0T + (size_t)sr * 65536 + n_base + sg * 8;
  f32x4 acc[4][4];
#pragma unroll
  for (int i = 0; i < 4; ++i)
#pragma unroll
    for (int j = 0; j < 4; ++j) acc[i][j] = (f32x4){0.f, 0.f, 0.f, 0.f};
  uint2 ra[8];
  uint4 rb[4];
#pragma unroll
  for (int u = 0; u < 8; ++u) ra[u] = *(const uint2*)(Ab + (size_t)u * 1024);
#pragma unroll
  for (int i = 0; i < 4; ++i) rb[i] = *(const uint4*)(Bb + (size_t)i * 32 * 65536);
#pragma unroll
  for (int v = 0; v < 4; ++v)
    wrA(&Al[0][(s4 * 4 + v) * 72 + n8 * 8], ra, v);
#pragma unroll
  for (int i = 0; i < 4; ++i)
    *(uint4*)&Bl[0][(sr + 32 * i) * 72 + sg * 8] = rb[i];
  __syncthreads();
  for (int c = 0; c < 16; ++c) {
    int p = c & 1;
    if (c < 15) {
      size_t koA = (size_t)(c + 1) * 64 * 1024;  // advance 64 n-rows in Qbf
      int koB = (c + 1) * 64;                    // advance 64 n-cols in x0T
#pragma unroll
      for (int u = 0; u < 8; ++u)
        ra[u] = *(const uint2*)(Ab + (size_t)u * 1024 + koA);
#pragma unroll
      for (int i = 0; i < 4; ++i)
        rb[i] = *(const uint4*)(Bb + (size_t)i * 32 * 65536 + koB);
    }
    mfma_tile128(Al[p], Bl[p], acc, wr, wc, lr, lq);
    if (c < 15) {
      int q = p ^ 1;
#pragma unroll
      for (int v = 0; v < 4; ++v)
        wrA(&Al[q][(s4 * 4 + v) * 72 + n8 * 8], ra, v);
#pragma unroll
      for (int i = 0; i < 4; ++i)
        *(uint4*)&Bl[q][(sr + 32 * i) * 72 + sg * 8] = rb[i];
    }
    __syncthreads();
  }
  float* outp = hp_part + (size_t)kb * 131072;
#pragma unroll
  for (int i = 0; i < 4; ++i) {
    int s_g = s0 + wr * 64 + i * 16 + lq * 4;
#pragma unroll
    for (int j = 0; j < 4; ++j) {
      int h = wc * 64 + j * 16 + lr;
#pragma unroll
      for (int r = 0; r < 4; ++r)
        outp[(size_t)(s_g + r) * 128 + h] = acc[i][j][r];
    }
  }
}

__global__ void k_hpred(const float* __restrict__ part,
                        const float* __restrict__ csum, float* __restrict__ hp) {
  int tid = blockIdx.x * 256 + threadIdx.x;
  float s = 0.f;
  for (int kb = 0; kb < 64; ++kb) s += part[(size_t)kb * 131072 + tid];
  hp[tid] = s / csum[tid >> 7];
}

// ---------------------------------------------------------------------------
// k_hyp_bf: hyp[n][h] = Qbf[n][s] . hpT[h][s]^T
// ---------------------------------------------------------------------------
__global__ __launch_bounds__(256) void k_hyp_bf(
    const ushort* __restrict__ Qbf, const ushort* __restrict__ hpT,
    float* __restrict__ hyp) {
  __shared__ ushort Al[2][128 * 72];
  __shared__ ushort Bl[2][128 * 72];
  int t = threadIdx.x;
  int n0 = blockIdx.x * 128;
  int wv = t >> 6, lane = t & 63;
  int wr = wv >> 1, wc = wv & 1;
  int lr = lane & 15, lq = lane >> 4;
  int sr = t >> 3, sg = t & 7;
  const ushort* Ab = Qbf + (size_t)(n0 + sr) * 1024 + sg * 8;
  const ushort* Bb = hpT + (size_t)sr * 1024 + sg * 8;
  f32x4 acc[4][4];
#pragma unroll
  for (int i = 0; i < 4; ++i)
#pragma unroll
    for (int j = 0; j < 4; ++j) acc[i][j] = (f32x4){0.f, 0.f, 0.f, 0.f};
  uint4 ra[4], rb[4];
#pragma unroll
  for (int i = 0; i < 4; ++i) {
    ra[i] = *(const uint4*)(Ab + (size_t)i * 32 * 1024);
    rb[i] = *(const uint4*)(Bb + (size_t)i * 32 * 1024);
  }
#pragma unroll
  for (int i = 0; i < 4; ++i) {
    *(uint4*)&Al[0][(sr + 32 * i) * 72 + sg * 8] = ra[i];
    *(uint4*)&Bl[0][(sr + 32 * i) * 72 + sg * 8] = rb[i];
  }
  __syncthreads();
  for (int c = 0; c < 16; ++c) {
    int p = c & 1;
    if (c < 15) {
      int ko = (c + 1) * 64;
#pragma unroll
      for (int i = 0; i < 4; ++i) {
        ra[i] = *(const uint4*)(Ab + (size_t)i * 32 * 1024 + ko);
        rb[i] = *(const uint4*)(Bb + (size_t)i * 32 * 1024 + ko);
      }
    }
    mfma_tile128(Al[p], Bl[p], acc, wr, wc, lr, lq);
    if (c < 15) {
      int q = p ^ 1;
#pragma unroll
      for (int i = 0; i < 4; ++i) {
        *(uint4*)&Al[q][(sr + 32 * i) * 72 + sg * 8] = ra[i];
        *(uint4*)&Bl[q][(sr + 32 * i) * 72 + sg * 8] = rb[i];
      }
    }
    __syncthreads();
  }
#pragma unroll
  for (int i = 0; i < 4; ++i) {
    int n_g = n0 + wr * 64 + i * 16 + lq * 4;
#pragma unroll
    for (int j = 0; j < 4; ++j) {
      int h = wc * 64 + j * 16 + lr;
#pragma unroll
      for (int r = 0; r < 4; ++r)
        hyp[(size_t)(n_g + r) * 128 + h] = acc[i][j][r];
    }
  }
}

// ---------------------------------------------------------------------------
// htmp = hp @ W_i + b_i     [1024,128]@[128,128]  (fp32, small)
// ---------------------------------------------------------------------------
__global__ __launch_bounds__(256) void k_slin(
    const float* __restrict__ A, const float* __restrict__ W,
    const float* __restrict__ bias, float* __restrict__ out) {
  __shared__ float Wl[128 * 128];
  __shared__ float Xl[32 * 128];
  int t = threadIdx.x;
  int n0 = blockIdx.x * 32;
  {
    const float4* Wg = (const float4*)W;
    float4* Wd = (float4*)Wl;
#pragma unroll
    for (int i = 0; i < 16; ++i) Wd[t + 256 * i] = Wg[t + 256 * i];
    const float4* Xg = (const float4*)(A + (size_t)n0 * 128);
    float4* Xd = (float4*)Xl;
#pragma unroll
    for (int i = 0; i < 4; ++i) Xd[t + 256 * i] = Xg[t + 256 * i];
  }
  __syncthreads();
  int ht = t & 31, nt = t >> 5;
  int h0 = ht * 4, r0 = nt * 4;
  float acc[4][4];
#pragma unroll
  for (int c = 0; c < 4; ++c) {
    float bv = bias[h0 + c];
#pragma unroll
    for (int r = 0; r < 4; ++r) acc[r][c] = bv;
  }
  for (int k = 0; k < 128; k += 4) {
    float4 xr[4], wk[4];
#pragma unroll
    for (int r = 0; r < 4; ++r) xr[r] = *(const float4*)&Xl[(r0 + r) * 128 + k];
#pragma unroll
    for (int kk = 0; kk < 4; ++kk) wk[kk] = *(const float4*)&Wl[(k + kk) * 128 + h0];
#pragma unroll
    for (int r = 0; r < 4; ++r) {
      float xs[4] = {xr[r].x, xr[r].y, xr[r].z, xr[r].w};
#pragma unroll
      for (int kk = 0; kk < 4; ++kk) {
        acc[r][0] += xs[kk] * wk[kk].x;
        acc[r][1] += xs[kk] * wk[kk].y;
        acc[r][2] += xs[kk] * wk[kk].z;
        acc[r][3] += xs[kk] * wk[kk].w;
      }
    }
  }
#pragma unroll
  for (int r = 0; r < 4; ++r) {
    *(float4*)&out[(size_t)(n0 + r0 + r) * 128 + h0] =
        make_float4(acc[r][0], acc[r][1], acc[r][2], acc[r][3]);
  }
}

// ---------------------------------------------------------------------------
// MMPN: fused dst-CSR gather + BN + lrelu (atomic-free).
// ---------------------------------------------------------------------------
__global__ __launch_bounds__(256) void k_mmpn_agg(
    const float* __restrict__ htmp, const float* __restrict__ hpin,
    const int* __restrict__ offA, const int* __restrict__ srcA,
    const float* __restrict__ valA, const int* __restrict__ offI,
    const int* __restrict__ srcI, const float* __restrict__ valI,
    const float* __restrict__ g, const float* __restrict__ b,
    const float* __restrict__ m, const float* __restrict__ v,
    float* __restrict__ hpout) {
  int s = blockIdx.x * 2 + (threadIdx.x >> 7);
  int h = threadIdx.x & 127;
  float acc = 0.f;
  int a0 = offA[s], a1 = offA[s + 1];
  for (int i = a0; i < a1; ++i)
    acc += valA[i] * htmp[(size_t)srcA[i] * 128 + h];
  int b0 = offI[s], b1 = offI[s + 1];
  for (int i = b0; i < b1; ++i)
    acc += valI[i] * hpin[(size_t)srcI[i] * 128 + h];
  float sc = g[h] * rsqrtf(v[h] + EPSV);
  float y = sc * (acc - m[h]) + b[h];
  hpout[(size_t)s * 128 + h] = y >= 0.f ? y : 0.01f * y;
}

// ---------------------------------------------------------------------------
// k_pxlin2: px linear [N,128]@[128,256] with fused LN + bf16 (q|v) pack.
// Writes pkrow/pkcol directly (lin4 never materialized in HBM).
// Epilogue reuses the weight LDS buffer (pitch 264 to spread banks).
// ---------------------------------------------------------------------------
#define LP 264
__global__ __launch_bounds__(256) void k_pxlin2(
    const float* __restrict__ px, const float* __restrict__ Wrv,
    const float* __restrict__ Wcv, const float* __restrict__ Wrq,
    const float* __restrict__ Wcq, const float* __restrict__ brv,
    const float* __restrict__ bcv, const float* __restrict__ brq,
    const float* __restrict__ bcq, uint* __restrict__ pkrow,
    uint* __restrict__ pkcol) {
  __shared__ float Xl[32 * 128];
  __shared__ float Wl[32 * LP];  // k-tile weights (32x256 used) / epilogue tile
  int t = threadIdx.x;
  int n0 = blockIdx.x * 32;
  {
    float4* Xd = (float4*)Xl;
    const float4* Xg = (const float4*)(px + (size_t)n0 * 128);
#pragma unroll
    for (int it = 0; it < 4; ++it) Xd[t + 256 * it] = Xg[t + 256 * it];
  }
  int ct = t & 63, nt = t >> 6;
  int c0 = ct * 4, r0 = nt * 8;
  float acc[8][4];
  {
    int mt = c0 >> 6, cb = c0 & 63;
    const float* bs = mt == 0 ? brv : mt == 1 ? bcv : mt == 2 ? brq : bcq;
#pragma unroll
    for (int c = 0; c < 4; ++c) {
      float bv = bs[cb + c];
#pragma unroll
      for (int r = 0; r < 8; ++r) acc[r][c] = bv;
    }
  }
  for (int kc = 0; kc < 4; ++kc) {
    int k0 = kc * 32;
    __syncthreads();
    {
#pragma unroll
      for (int it = 0; it < 8; ++it) {
        int v = t + 256 * it;
        int kk = v >> 6, cq = v & 63;
        int c = cq * 4;
        int mt = c >> 6, cb = c & 63;
        const float* Ws = mt == 0 ? Wrv : mt == 1 ? Wcv : mt == 2 ? Wrq : Wcq;
        *(float4*)&Wl[kk * 256 + c] = *(const float4*)&Ws[(size_t)(k0 + kk) * 64 + cb];
      }
    }
    __syncthreads();
    for (int k = 0; k < 32; k += 4) {
      float4 wq[4];
#pragma unroll
      for (int kk = 0; kk < 4; ++kk) wq[kk] = *(const float4*)&Wl[(k + kk) * 256 + c0];
#pragma unroll
      for (int r = 0; r < 8; ++r) {
        float4 xq = *(const float4*)&Xl[(r0 + r) * 128 + k0 + k];
        float xs[4] = {xq.x, xq.y, xq.z, xq.w};
#pragma unroll
        for (int kk = 0; kk < 4; ++kk) {
          acc[r][0] += xs[kk] * wq[kk].x;
          acc[r][1] += xs[kk] * wq[kk].y;
          acc[r][2] += xs[kk] * wq[kk].z;
          acc[r][3] += xs[kk] * wq[kk].w;
        }
      }
    }
  }
  // ---- fused LN + pack epilogue ----
  __syncthreads();  // all reads of Wl k-tile done
#pragma unroll
  for (int r = 0; r < 8; ++r)
    *(float4*)&Wl[(r0 + r) * LP + c0] =
        make_float4(acc[r][0], acc[r][1], acc[r][2], acc[r][3]);
  __syncthreads();
  int rr = t >> 3, l8 = t & 7;  // 32 rows x 8 lanes/row (8-lane groups in-wave)
  const float* Lr = &Wl[rr * LP];
#pragma unroll
  for (int h = 0; h < 2; ++h) {
    float4 qa = *(const float4*)&Lr[128 + h * 64 + l8 * 8];
    float4 qb = *(const float4*)&Lr[128 + h * 64 + l8 * 8 + 4];
    float s = qa.x + qa.y + qa.z + qa.w + qb.x + qb.y + qb.z + qb.w;
    float s2 = qa.x * qa.x + qa.y * qa.y + qa.z * qa.z + qa.w * qa.w +
               qb.x * qb.x + qb.y * qb.y + qb.z * qb.z + qb.w * qb.w;
#pragma unroll
    for (int o = 1; o < 8; o <<= 1) {
      s += __shfl_xor(s, o, 64);
      s2 += __shfl_xor(s2, o, 64);
    }
    float mu = s * (1.0f / 64.0f);
    float var = s2 * (1.0f / 64.0f) - mu * mu;
    float rstd = rsqrtf(var + EPSV);
    float4 va = *(const float4*)&Lr[h * 64 + l8 * 8];
    float4 vb = *(const float4*)&Lr[h * 64 + l8 * 8 + 4];
    uint4 o1, o2;
    o1.x = (uint)f2bf((qa.x - mu) * rstd) | ((uint)f2bf(va.x) << 16);
    o1.y = (uint)f2bf((qa.y - mu) * rstd) | ((uint)f2bf(va.y) << 16);
    o1.z = (uint)f2bf((qa.z - mu) * rstd) | ((uint)f2bf(va.z) << 16);
    o1.w = (uint)f2bf((qa.w - mu) * rstd) | ((uint)f2bf(va.w) << 16);
    o2.x = (uint)f2bf((qb.x - mu) * rstd) | ((uint)f2bf(vb.x) << 16);
    o2.y = (uint)f2bf((qb.y - mu) * rstd) | ((uint)f2bf(vb.y) << 16);
    o2.z = (uint)f2bf((qb.z - mu) * rstd) | ((uint)f2bf(vb.z) << 16);
    o2.w = (uint)f2bf((qb.w - mu) * rstd) | ((uint)f2bf(vb.w) << 16);
    uint* dst = (h ? pkcol : pkrow) + (size_t)(n0 + rr) * 64 + l8 * 8;
    *(uint4*)&dst[0] = o1;
    *(uint4*)&dst[4] = o2;
  }
}

// ---------------------------------------------------------------------------
// CSR build: histogram -> exclusive scan -> fill
// ---------------------------------------------------------------------------
__global__ void k_hist(const int* __restrict__ src, int* __restrict__ cnt) {
  int e = blockIdx.x * 256 + threadIdx.x;
  atomicAdd(&cnt[src[e]], 1);
}

__global__ __launch_bounds__(1024) void k_scan(const int* __restrict__ cnt,
                                               int* __restrict__ off,
                                               int* __restrict__ cur) {
  __shared__ int part[1024];
  int t = threadIdx.x;
  int base = t * 64;
  int s = 0;
  for (int i = 0; i < 64; ++i) s += cnt[base + i];
  part[t] = s;
  __syncthreads();
  for (int o = 1; o < 1024; o <<= 1) {
    int v = part[t];
    int add = (t >= o) ? part[t - o] : 0;
    __syncthreads();
    part[t] = v + add;
    __syncthreads();
  }
  int run = (t > 0) ? part[t - 1] : 0;
  for (int i = 0; i < 64; ++i) {
    off[base + i] = run;
    cur[base + i] = run;
    run += cnt[base + i];
  }
  if (t == 1023) off[65536] = run;
}

// small scan over exactly 1024 counters (for MMPN CSRs)
__global__ __launch_bounds__(1024) void k_scan_s(const int* __restrict__ cnt,
                                                 int* __restrict__ off,
                                                 int* __restrict__ cur) {
  __shared__ int part[1024];
  int t = threadIdx.x;
  int v = cnt[t];
  part[t] = v;
  __syncthreads();
  for (int o = 1; o < 1024; o <<= 1) {
    int x = part[t];
    int a = (t >= o) ? part[t - o] : 0;
    __syncthreads();
    part[t] = x + a;
    __syncthreads();
  }
  int ex = (t > 0) ? part[t - 1] : 0;
  off[t] = ex;
  cur[t] = ex;
  if (t == 1023) off[1024] = part[1023];
}

__global__ void k_fill(const int* __restrict__ src, const int* __restrict__ dst,
                       int* __restrict__ cur, int* __restrict__ csr) {
  int e = blockIdx.x * 256 + threadIdx.x;
  int p = atomicAdd(&cur[src[e]], 1);
  csr[p] = dst[e];
}

// fill with (src, val) payload, keyed by dst (for MMPN)
__global__ void k_fill_v(const int* __restrict__ dst, const int* __restrict__ src,
                         const float* __restrict__ val, int* __restrict__ cur,
                         int* __restrict__ csr_src, float* __restrict__ csr_val) {
  int e = blockIdx.x * 256 + threadIdx.x;
  int p = atomicAdd(&cur[dst[e]], 1);
  csr_src[p] = src[e];
  csr_val[p] = val[e];
}

// ---------------------------------------------------------------------------
// Fused segment-softmax attention gather over packed bf16 (q|v) records.
// ---------------------------------------------------------------------------
__global__ __launch_bounds__(256) void k_gather2(
    const uint* __restrict__ pk, const int* __restrict__ off,
    const int* __restrict__ csr, const float* __restrict__ g,
    const float* __restrict__ b, const float* __restrict__ m,
    const float* __restrict__ v, int ooff, float* __restrict__ outp) {
  int node = blockIdx.x * 4 + (threadIdx.x >> 6);
  int l = threadIdx.x & 63;
  uint rs = pk[(size_t)node * 64 + l];
  float qs = bf2f(rs & 0xffffu);
  int i0 = off[node], i1 = off[node + 1];
  float acc = 0.f, den = 0.f;
  int i = i0;
  for (; i + 2 <= i1; i += 2) {
    int d0 = csr[i], d1 = csr[i + 1];
    uint r0 = pk[(size_t)d0 * 64 + l];
    uint r1 = pk[(size_t)d1 * 64 + l];
    float p0 = qs * bf2f(r0 & 0xffffu);
    float p1 = qs * bf2f(r1 & 0xffffu);
#pragma unroll
    for (int o = 32; o > 0; o >>= 1) {
      p0 += __shfl_xor(p0, o, 64);
      p1 += __shfl_xor(p1, o, 64);
    }
    float w0 = __expf(p0 * (1.0f / OUTW));
    float w1 = __expf(p1 * (1.0f / OUTW));
    den += w0 + w1;
    acc += w0 * bf2f(r0 >> 16) + w1 * bf2f(r1 >> 16);
  }
  if (i < i1) {
    int d0 = csr[i];
    uint r0 = pk[(size_t)d0 * 64 + l];
    float p0 = qs * bf2f(r0 & 0xffffu);
#pragma unroll
    for (int o = 32; o > 0; o >>= 1) p0 += __shfl_xor(p0, o, 64);
    float w0 = __expf(p0 * (1.0f / OUTW));
    den += w0;
    acc += w0 * bf2f(r0 >> 16);
  }
  float r = den > 0.f ? 1.0f / den : 0.f;
  float val = acc * r;
  int h = ooff + l;
  float sc = g[h] * rsqrtf(v[h] + EPSV);
  float y = sc * (val - m[h]) + b[h];
  outp[(size_t)node * HIDE + h] = y >= 0.f ? y : 0.01f * y;
}

// final: out = softmax((hyp+px) @ final_w + final_b)
__global__ __launch_bounds__(256) void k_final(
    const float* __restrict__ hyp, const float* __restrict__ px,
    const float* __restrict__ W, const float* __restrict__ b,
    float* __restrict__ out) {
  __shared__ float Wl[128 * 16];
  __shared__ float rl[16 * 129];
  int t = threadIdx.x;
  int n0 = blockIdx.x * 16;
#pragma unroll
  for (int i = 0; i < 8; ++i) Wl[t + 256 * i] = W[t + 256 * i];
#pragma unroll
  for (int i = 0; i < 8; ++i) {
    int v = t + 256 * i;
    int r = v >> 7, c = v & 127;
    rl[r * 129 + c] = hyp[(size_t)(n0 + r) * 128 + c] + px[(size_t)(n0 + r) * 128 + c];
  }
  __syncthreads();
  int r = t >> 4, cls = t & 15;
  float acc = b[cls];
  for (int k = 0; k < 128; ++k) acc += rl[r * 129 + k] * Wl[k * 16 + cls];
  float mx = acc;
#pragma unroll
  for (int o = 8; o > 0; o >>= 1) mx = fmaxf(mx, __shfl_xor(mx, o, 16));
  float e = expf(acc - mx), s = e;
#pragma unroll
  for (int o = 8; o > 0; o >>= 1) s += __shfl_xor(s, o, 16);
  out[(size_t)(n0 + r) * 16 + cls] = e / s;
}

// ---------------------------------------------------------------------------
extern "C" void kernel_launch(void* const* d_in, const int* in_sizes, int n_in,
                              void* d_out, int out_size, void* d_ws, size_t ws_size,
                              hipStream_t stream) {
  const float* x        = (const float*)d_in[0];
  const float* Q        = (const float*)d_in[1];
  const float* prelin_w = (const float*)d_in[2];
  const float* prelin_b = (const float*)d_in[3];
  const float* bn0_g    = (const float*)d_in[4];
  const float* bn0_b    = (const float*)d_in[5];
  const float* bn0_m    = (const float*)d_in[6];
  const float* bn0_v    = (const float*)d_in[7];
  const float* mmpn_w   = (const float*)d_in[8];
  const float* mmpn_b   = (const float*)d_in[9];
  const float* mmpn_bn_g= (const float*)d_in[10];
  const float* mmpn_bn_b= (const float*)d_in[11];
  const float* mmpn_bn_m= (const float*)d_in[12];
  const float* mmpn_bn_v= (const float*)d_in[13];
  const float* A_val    = (const float*)d_in[14];
  const float* imp_val  = (const float*)d_in[15];
  const float* px_rowv_w= (const float*)d_in[16];
  const float* px_rowv_b= (const float*)d_in[17];
  const float* px_colv_w= (const float*)d_in[18];
  const float* px_colv_b= (const float*)d_in[19];
  const float* px_rowq_w= (const float*)d_in[20];
  const float* px_rowq_b= (const float*)d_in[21];
  const float* px_colq_w= (const float*)d_in[22];
  const float* px_colq_b= (const float*)d_in[23];
  const float* px_bn_g  = (const float*)d_in[24];
  const float* px_bn_b  = (const float*)d_in[25];
  const float* px_bn_m  = (const float*)d_in[26];
  const float* px_bn_v  = (const float*)d_in[27];
  const float* final_w  = (const float*)d_in[28];
  const float* final_b  = (const float*)d_in[29];
  const int* A_src   = (const int*)d_in[30];
  const int* A_dst   = (const int*)d_in[31];
  const int* imp_src = (const int*)d_in[32];
  const int* imp_dst = (const int*)d_in[33];
  const int* row_src = (const int*)d_in[34];
  const int* row_dst = (const int*)d_in[35];
  const int* col_src = (const int*)d_in[36];
  const int* col_dst = (const int*)d_in[37];
  float* out = (float*)d_out;

  float* ws = (float*)d_ws;
  float* x0px = ws; ws += (size_t)N_PIX * HIDE;          // 32 MB fp32
  float* hyp  = ws; ws += (size_t)N_PIX * HIDE;          // 32 MB fp32 (aliases hp_part)
  float* hp_part = hyp;                                   // live only hpu->hpred
  float* big  = ws; ws += (size_t)32 * 1024 * 1024;       // 128 MiB region
  // phase 1: Qbf bf16 [N][1024] occupies big[0..128 MB); dead after k_hyp_bf.
  ushort* Qbf = (ushort*)big;
  // phase 2 (after k_hyp_bf): CSR + packed q|v records overlay the region.
  int* off_row = (int*)(big + (size_t)N_PIX * 256);        // +64 MB
  int* off_col = off_row + 65537;
  int* csr_row = off_col + 65537;
  int* csr_col = csr_row + E_PX;                           // ends ~72.5 MB
  uint* pkrow = (uint*)(big + (size_t)20 * 1024 * 1024);   // +80 MB, 16 MB
  uint* pkcol = pkrow + (size_t)N_PIX * 64;                // +96 MB, 16 MB
  ushort* x0T = (ushort*)ws; ws += (size_t)HIDE * N_PIX / 2;  // bf16 [128][65536]
  ushort* hpT = (ushort*)ws; ws += (size_t)HIDE * S_SP / 2;   // bf16 [128][1024]
  float* csum = ws; ws += S_SP;
  float* hp   = ws; ws += (size_t)S_SP * HIDE;
  float* htmp = ws; ws += (size_t)S_SP * HIDE;   // reused as cur_row/cur_col
  float* agg  = ws; ws += (size_t)S_SP * HIDE;   // MMPN ping-pong; later cnt_row/col

  // MMPN dst-CSR arrays (tiny)
  int* offA = (int*)ws;
  int* offI = offA + 1025;
  int* cntA = offI + 1025;   // cntA,cntI contiguous for single memset
  int* cntI = cntA + 1024;
  int* curA = cntI + 1024;
  int* curI = curA + 1024;
  int* srcA = curI + 1024;
  float* valA = (float*)(srcA + E_A);
  int* srcI = (int*)(valA + E_A);
  float* valI = (float*)(srcI + E_IMP);

  int* cnt_row = (int*)agg;
  int* cnt_col = (int*)agg + 65536;
  int* cur_row = (int*)htmp;
  int* cur_col = (int*)htmp + 65536;

  hipMemsetAsync(csum, 0, S_SP * sizeof(float), stream);
  hipMemsetAsync(cntA, 0, 2 * 1024 * sizeof(int), stream);

  // MMPN dst-CSR build (edges are tiny; once per launch)
  k_hist<<<E_A / 256, 256, 0, stream>>>(A_dst, cntA);
  k_hist<<<E_IMP / 256, 256, 0, stream>>>(imp_dst, cntI);
  k_scan_s<<<1, 1024, 0, stream>>>(cntA, offA, curA);
  k_scan_s<<<1, 1024, 0, stream>>>(cntI, offI, curI);
  k_fill_v<<<E_A / 256, 256, 0, stream>>>(A_dst, A_src, A_val, curA, srcA, valA);
  k_fill_v<<<E_IMP / 256, 256, 0, stream>>>(imp_dst, imp_src, imp_val, curI, srcI, valI);

  k_cast2<<<N_PIX / 64, 256, 0, stream>>>(Q, Qbf, csum);
  k_x0<<<N_PIX / 32, 256, 0, stream>>>(x, prelin_w, prelin_b, bn0_g, bn0_b, bn0_m,
                                       bn0_v, x0px);
  k_xT<<<N_PIX / 256, 256, 0, stream>>>(x0px, x0T);
  k_hpu3<<<512, 256, 0, stream>>>(Qbf, x0T, hp_part);
  k_hpred<<<S_SP * HIDE / 256, 256, 0, stream>>>(hp_part, csum, hp);

  {
    float* cur = hp;
    float* nxt = agg;
    for (int i = 0; i < 5; ++i) {
      k_slin<<<S_SP / 32, 256, 0, stream>>>(cur, mmpn_w + (size_t)i * HIDE * HIDE,
                                            mmpn_b + i * HIDE, htmp);
      k_mmpn_agg<<<S_SP / 2, 256, 0, stream>>>(
          htmp, cur, offA, srcA, valA, offI, srcI, valI,
          mmpn_bn_g + i * HIDE, mmpn_bn_b + i * HIDE, mmpn_bn_m + i * HIDE,
          mmpn_bn_v + i * HIDE, nxt);
      float* tmp = cur; cur = nxt; nxt = tmp;
    }
    k_hpT<<<S_SP / 256, 256, 0, stream>>>(cur, hpT);
  }
  k_hyp_bf<<<N_PIX / 128, 256, 0, stream>>>(Qbf, hpT, hyp);

  // ---- pixel CSR build (Qbf region now reusable; cnt/cur alias agg/htmp) ----
  hipMemsetAsync(cnt_row, 0, 2 * 65536 * sizeof(int), stream);
  k_hist<<<E_PX / 256, 256, 0, stream>>>(row_src, cnt_row);
  k_hist<<<E_PX / 256, 256, 0, stream>>>(col_src, cnt_col);
  k_scan<<<1, 1024, 0, stream>>>(cnt_row, off_row, cur_row);
  k_scan<<<1, 1024, 0, stream>>>(cnt_col, off_col, cur_col);
  k_fill<<<E_PX / 256, 256, 0, stream>>>(row_src, row_dst, cur_row, csr_row);
  k_fill<<<E_PX / 256, 256, 0, stream>>>(col_src, col_dst, cur_col, csr_col);

  for (int j = 0; j < 2; ++j) {
    k_pxlin2<<<N_PIX / 32, 256, 0, stream>>>(
        x0px, px_rowv_w + j * 8192, px_colv_w + j * 8192, px_rowq_w + j * 8192,
        px_colq_w + j * 8192, px_rowv_b + j * 64, px_colv_b + j * 64,
        px_rowq_b + j * 64, px_colq_b + j * 64, pkrow, pkcol);
    k_gather2<<<N_PIX / 4, 256, 0, stream>>>(
        pkrow, off_row, csr_row, px_bn_g + j * HIDE, px_bn_b + j * HIDE,
        px_bn_m + j * HIDE, px_bn_v + j * HIDE, 0, x0px);
    k_gather2<<<N_PIX / 4, 256, 0, stream>>>(
        pkcol, off_col, csr_col, px_bn_g + j * HIDE, px_bn_b + j * HIDE,
        px_bn_m + j * HIDE, px_bn_v + j * HIDE, 64, x0px);
  }

  k_final<<<N_PIX / 16, 256, 0, stream>>>(hyp, x0px, final_w, final_b, out);
}